// Round 14
// baseline (349.882 us; speedup 1.0000x reference)
//
#include <hip/hip_runtime.h>
#include <hip/hip_fp16.h>
#include <math.h>

#define D 128
#define NSL 32          // edge slices
#define PBU 25088       // packed u8 counters (uints) -> supports N <= 100352

typedef _Float16 half8 __attribute__((ext_vector_type(8)));
typedef float f32x4 __attribute__((ext_vector_type(4)));

__device__ inline uint pack_f16x2(float a, float b) {
  __half2 h = __floats2half2_rn(a, b);
  return *reinterpret_cast<uint*>(&h);
}
__device__ inline float2 unpack_f16x2(uint p) {
  __half2 h = *reinterpret_cast<__half2*>(&p);
  return __half22float2(h);
}
__device__ inline uint mdiv40(uint x, uint M) {  // x / d with M = ceil(2^40/d)
  return (uint)(((unsigned long long)x * M) >> 40);
}

// ---------------- build1: fused {dst-hist+rank, src-hist, Wt transpose, CA/CB} ----------

__global__ __launch_bounds__(1024) void k_build1(const int* __restrict__ esrc,
                                                 const int* __restrict__ edst,
                                                 const float* __restrict__ W0,
                                                 const float* __restrict__ W1,
                                                 const float* __restrict__ W2,
                                                 const float* __restrict__ b0,
                                                 const float* __restrict__ b1,
                                                 const float* __restrict__ b2,
                                                 const float* __restrict__ g0,
                                                 const float* __restrict__ be0,
                                                 const float* __restrict__ mu0,
                                                 const float* __restrict__ vr0,
                                                 const float* __restrict__ g1,
                                                 const float* __restrict__ be1,
                                                 const float* __restrict__ mu1,
                                                 const float* __restrict__ vr1,
                                                 uint* __restrict__ pd,
                                                 uint* __restrict__ ps,
                                                 uchar* __restrict__ rank8,
                                                 ushort* __restrict__ Wt,
                                                 float* __restrict__ CA,
                                                 float* __restrict__ CB,
                                                 int E, int SB) {
  __shared__ uint h[PBU];   // ~98 KB static LDS (hist blocks only)
  const int b = blockIdx.x;
  const int t = threadIdx.x;
  if (b < 32) {             // ---- dst histogram + rank record
    for (int j = t; j < PBU; j += 1024) h[j] = 0u;
    __syncthreads();
    const int i0 = b * SB, i1 = min(i0 + SB, E);
    for (int i = i0 + t; i < i1; i += 1024) {
      const int d = edst[i];
      const uint sh = (uint)(d & 3) * 8u;
      const uint old = atomicAdd(&h[d >> 2], 1u << sh);
      rank8[i] = (uchar)((old >> sh) & 0xffu);
    }
    __syncthreads();
    uint* p = pd + (size_t)b * PBU;
    for (int j = t; j < PBU; j += 1024) p[j] = h[j];
  } else if (b < 64) {      // ---- src histogram (counts only)
    const int sl = b - 32;
    for (int j = t; j < PBU; j += 1024) h[j] = 0u;
    __syncthreads();
    const int i0 = sl * SB, i1 = min(i0 + SB, E);
    for (int i = i0 + t; i < i1; i += 1024) {
      const int s = esrc[i];
      atomicAdd(&h[s >> 2], 1u << ((uint)(s & 3) * 8u));
    }
    __syncthreads();
    uint* p = ps + (size_t)sl * PBU;
    for (int j = t; j < PBU; j += 1024) p[j] = h[j];
  } else if (b < 112) {     // ---- Wt[l][n][k] = f16(W_l[k][n])
    const int li = (b - 64) * 1024 + t;   // 0..49151
    const int l = li >> 14;
    const int i = li & 16383;
    const int n = i >> 7, k = i & 127;
    const float* W = (l == 0) ? W0 : ((l == 1) ? W1 : W2);
    Wt[li] = __half_as_ushort(__float2half_rn(W[k * D + n]));
  } else if (t < D) {       // ---- CA/CB fold bias+BN
    const int c = t;
    float A0 = g0[c] * rsqrtf(vr0[c] + 1e-5f);
    CA[c] = A0;
    CB[c] = (b0[c] - mu0[c]) * A0 + be0[c];
    float A1 = g1[c] * rsqrtf(vr1[c] + 1e-5f);
    CA[D + c] = A1;
    CB[D + c] = (b1[c] - mu1[c]) * A1 + be1[c];
    CA[2 * D + c] = 1.f;
    CB[2 * D + c] = b2[c];
  }
}

// ---- build2s: reduceN + chunk sum; LAST block serial-scans chunk sums ----

__global__ __launch_bounds__(256) void k_build2s(uint* __restrict__ pd,
                                                 const uint* __restrict__ ps,
                                                 int* __restrict__ totd,
                                                 float* __restrict__ ns,
                                                 float* __restrict__ nd,
                                                 int* __restrict__ csum,
                                                 int* __restrict__ rofs,
                                                 int* __restrict__ ticket,
                                                 int N, int nch) {
  __shared__ int sd[256];
  __shared__ int lastf;
  const int t = threadIdx.x;
  const int j = blockIdx.x * 256 + t;    // packed uint index (4 nodes), j < PBU
  const int n0 = j * 4;
  uint r0 = 0, r1 = 0, r2 = 0, r3 = 0;
  uint s0 = 0, s1 = 0, s2 = 0, s3 = 0;
#pragma unroll
  for (int sl = 0; sl < NSL; ++sl) {
    const uint v = pd[(size_t)sl * PBU + j];
    pd[(size_t)sl * PBU + j] = r0 | (r1 << 8) | (r2 << 16) | (r3 << 24);
    r0 += v & 0xffu; r1 += (v >> 8) & 0xffu; r2 += (v >> 16) & 0xffu; r3 += (v >> 24) & 0xffu;
    const uint w = ps[(size_t)sl * PBU + j];
    s0 += w & 0xffu; s1 += (w >> 8) & 0xffu; s2 += (w >> 16) & 0xffu; s3 += (w >> 24) & 0xffu;
  }
  const uint rr[4] = {r0, r1, r2, r3};
  const uint ss[4] = {s0, s1, s2, s3};
  int tot = 0;
#pragma unroll
  for (int k = 0; k < 4; ++k) {
    if (n0 + k < N) {
      totd[n0 + k] = (int)rr[k];
      nd[n0 + k] = rsqrtf((float)max(rr[k], 1u));
      ns[n0 + k] = rsqrtf((float)max(ss[k], 1u));
      tot += (int)rr[k];
    }
  }
  sd[t] = tot; __syncthreads();
  for (int off = 128; off > 0; off >>= 1) {
    if (t < off) sd[t] += sd[t + off];
    __syncthreads();
  }
  if (t == 0) {
    csum[blockIdx.x] = sd[0];
    __threadfence();
    lastf = (atomicAdd(ticket, 1) == nch - 1) ? 1 : 0;
  }
  __syncthreads();
  if (lastf && t < 64) {
    __threadfence();
    int run = 0;
    for (int b0 = 0; b0 < nch; b0 += 64) {
      const int idx = b0 + t;
      int v = (idx < nch) ? __hip_atomic_load(&csum[idx], __ATOMIC_RELAXED,
                                              __HIP_MEMORY_SCOPE_AGENT) : 0;
      int sc = v;
#pragma unroll
      for (int off = 1; off < 64; off <<= 1) {
        int u = __shfl_up(sc, off);
        if (t >= off) sc += u;
      }
      if (idx < nch) csum[idx] = run + sc - v;
      run += __shfl(sc, 63);
    }
    if (t == 0) rofs[N] = run;
  }
}

// ---------------- final per-node rofs scan ----------------

__global__ __launch_bounds__(256) void k_scan_final(const int* __restrict__ totd,
                                                    const int* __restrict__ csum,
                                                    int* __restrict__ rofs, int n) {
  __shared__ int sd[256];
  const int b = blockIdx.x, t = threadIdx.x;
  const int base = b * 1024 + t * 4;
  int v[4]; int s = 0;
#pragma unroll
  for (int i = 0; i < 4; ++i) { v[i] = (base + i < n) ? totd[base + i] : 0; s += v[i]; }
  sd[t] = s; __syncthreads();
  for (int off = 1; off < 256; off <<= 1) {
    int x = (t >= off) ? sd[t - off] : 0;
    __syncthreads();
    sd[t] += x;
    __syncthreads();
  }
  int o = sd[t] - s + csum[b];
#pragma unroll
  for (int i = 0; i < 4; ++i) {
    if (base + i < n) { rofs[base + i] = o; o += v[i]; }
  }
}

// ---- sg: merged {layer-0 GEMM (f32 input, ns folded), CHUNK-MAJOR out} + {scatter} ----

__global__ __launch_bounds__(256) void k_sg(const float* __restrict__ X,
                                            const ushort* __restrict__ Wt,
                                            const float* __restrict__ ns,
                                            ushort* __restrict__ out,
                                            const int* __restrict__ esrc,
                                            const int* __restrict__ edst,
                                            const uchar* __restrict__ rank8,
                                            const uint* __restrict__ pd,
                                            const int* __restrict__ rofs,
                                            int* __restrict__ csr,
                                            int M, int E, uint Msb, int GB) {
  if ((int)blockIdx.x >= GB) {   // ---- scatter part
    const int i = ((int)blockIdx.x - GB) * 256 + threadIdx.x;
    if (i < E) {
      const int d = edst[i];
      const uint sl = mdiv40((uint)i, Msb);
      const uint pk = pd[(size_t)sl * PBU + (d >> 2)];
      const uint pfx = (pk >> ((uint)(d & 3) * 8u)) & 0xffu;
      csr[rofs[d] + (int)pfx + (int)rank8[i]] = esrc[i];
    }
    return;
  }
  // ---- gemm32 part
  const int lane = threadIdx.x & 63;
  const int wv = threadIdx.x >> 6;
  const int m0 = (blockIdx.x * 4 + wv) * 32;
  if (m0 >= M) return;
  const int lr = lane & 15;
  const int kg = (lane >> 4) * 8;

  half8 hf[2][4];
  const half8 hz = {};
#pragma unroll
  for (int mt = 0; mt < 2; ++mt) {
    const int row = m0 + mt * 16 + lr;
    if (row < M) {
      const float s = ns[row];
#pragma unroll
      for (int kt = 0; kt < 4; ++kt) {
        const float4 a = *reinterpret_cast<const float4*>(X + (size_t)row * D + kt * 32 + kg);
        const float4 b = *reinterpret_cast<const float4*>(X + (size_t)row * D + kt * 32 + kg + 4);
        half8 hv;
        hv[0] = (_Float16)(a.x * s); hv[1] = (_Float16)(a.y * s);
        hv[2] = (_Float16)(a.z * s); hv[3] = (_Float16)(a.w * s);
        hv[4] = (_Float16)(b.x * s); hv[5] = (_Float16)(b.y * s);
        hv[6] = (_Float16)(b.z * s); hv[7] = (_Float16)(b.w * s);
        hf[mt][kt] = hv;
      }
    } else {
#pragma unroll
      for (int kt = 0; kt < 4; ++kt) hf[mt][kt] = hz;
    }
  }

  f32x4 acc[8][2];
#pragma unroll
  for (int nt = 0; nt < 8; ++nt) { acc[nt][0] = (f32x4)(0.f); acc[nt][1] = (f32x4)(0.f); }

#pragma unroll
  for (int nt = 0; nt < 8; ++nt) {
    const ushort* wb = Wt + (size_t)(nt * 16 + lr) * D + kg;
#pragma unroll
    for (int kt = 0; kt < 4; ++kt) {
      half8 wf = *reinterpret_cast<const half8*>(wb + kt * 32);
      acc[nt][0] = __builtin_amdgcn_mfma_f32_16x16x32_f16(wf, hf[0][kt], acc[nt][0], 0, 0, 0);
      acc[nt][1] = __builtin_amdgcn_mfma_f32_16x16x32_f16(wf, hf[1][kt], acc[nt][1], 0, 0, 0);
    }
  }

  const int mo = lane & 15;
  const int no = (lane >> 4) * 4;   // col offset within 16-col chunk
#pragma unroll
  for (int mt = 0; mt < 2; ++mt) {
    const int row = m0 + mt * 16 + mo;
    if (row < M) {
#pragma unroll
      for (int nt = 0; nt < 8; ++nt) {
        uint2 u;
        u.x = pack_f16x2(acc[nt][mt][0], acc[nt][mt][1]);
        u.y = pack_f16x2(acc[nt][mt][2], acc[nt][mt][3]);
        // chunk-major: chunk nt, node row, 16 halfs/node
        *reinterpret_cast<uint2*>(out + ((size_t)nt * M + row) * 16 + no) = u;
      }
    }
  }
}

// ---------------- MFMA GEMM (f16 chunk-major in, f16 chunk-major out) ----------------

__global__ __launch_bounds__(256) void k_gemm16(const ushort* __restrict__ A,
                                                const ushort* __restrict__ Wt,
                                                ushort* __restrict__ out, int M) {
  const int lane = threadIdx.x & 63;
  const int wv = threadIdx.x >> 6;
  const int m0 = (blockIdx.x * 4 + wv) * 32;
  if (m0 >= M) return;
  const int lr = lane & 15;
  const int kg = (lane >> 4) * 8;

  half8 hf[2][4];
  const half8 hz = {};
#pragma unroll
  for (int mt = 0; mt < 2; ++mt) {
    const int row = m0 + mt * 16 + lr;
    const bool ok = row < M;
#pragma unroll
    for (int kt = 0; kt < 4; ++kt) {
      const int off = kt * 32 + kg;
      const int c = off >> 4, o = off & 15;
      hf[mt][kt] = ok ? *reinterpret_cast<const half8*>(A + ((size_t)c * M + row) * 16 + o)
                      : hz;
    }
  }

  f32x4 acc[8][2];
#pragma unroll
  for (int nt = 0; nt < 8; ++nt) { acc[nt][0] = (f32x4)(0.f); acc[nt][1] = (f32x4)(0.f); }

#pragma unroll
  for (int nt = 0; nt < 8; ++nt) {
    const ushort* wb = Wt + (size_t)(nt * 16 + lr) * D + kg;
#pragma unroll
    for (int kt = 0; kt < 4; ++kt) {
      half8 wf = *reinterpret_cast<const half8*>(wb + kt * 32);
      acc[nt][0] = __builtin_amdgcn_mfma_f32_16x16x32_f16(wf, hf[0][kt], acc[nt][0], 0, 0, 0);
      acc[nt][1] = __builtin_amdgcn_mfma_f32_16x16x32_f16(wf, hf[1][kt], acc[nt][1], 0, 0, 0);
    }
  }

  const int mo = lane & 15;
  const int no = (lane >> 4) * 4;
#pragma unroll
  for (int mt = 0; mt < 2; ++mt) {
    const int row = m0 + mt * 16 + mo;
    if (row < M) {
#pragma unroll
      for (int nt = 0; nt < 8; ++nt) {
        uint2 u;
        u.x = pack_f16x2(acc[nt][mt][0], acc[nt][mt][1]);
        u.y = pack_f16x2(acc[nt][mt][2], acc[nt][mt][3]);
        *reinterpret_cast<uint2*>(out + ((size_t)nt * M + row) * 16 + no) = u;
      }
    }
  }
}

// ---- SpMM, column-sliced: pass p = blockIdx%8 touches ONLY chunk p (3.2 MB -> one L2).
// 16-lane group per dst row: lane = (slot, half); 2 slots/lane -> 16 edges per iter;
// each lane loads its own csr index directly (no shfl); 3-step shfl_xor slot-reduce.

__global__ __launch_bounds__(256) void k_spmmc(const uint* __restrict__ hs,
                                               const int* __restrict__ csr,
                                               const int* __restrict__ rofs,
                                               const float* __restrict__ nd,
                                               const float* __restrict__ ns,
                                               const float* __restrict__ CA,
                                               const float* __restrict__ CB,
                                               float* __restrict__ outf,
                                               uint* __restrict__ hnext,
                                               int N, int RB, int last) {
  const int t = threadIdx.x;
  const int lane = t & 63;
  const int il = lane & 15;
  const int slot = il >> 1;        // 0..7
  const int half = il & 1;         // 16B half of the 32B slice
  const int p = blockIdx.x & 7;    // col chunk == XCD (if %8 mapping holds)
  const uint* hsC = hs + (size_t)p * N * 8;
  const int g = t >> 4;            // group 0..15
  const int rb0 = (blockIdx.x >> 3) * (16 * RB);

#pragma unroll 1
  for (int r = 0; r < RB; ++r) {
    const int d = rb0 + r * 16 + g;   // uniform within the 16-lane group
    if (d >= N) break;
    const int beg = rofs[d], end = rofs[d + 1];
    float acc[8];
#pragma unroll
    for (int j = 0; j < 8; ++j) acc[j] = 0.f;
#pragma unroll 1
    for (int eb = beg; eb < end; eb += 16) {
      const int e0 = eb + slot;
      const int e1 = eb + slot + 8;
      const int s0 = csr[min(e0, end - 1)];
      const int s1 = csr[min(e1, end - 1)];
      const float w0 = (e0 < end) ? 1.f : 0.f;
      const float w1 = (e1 < end) ? 1.f : 0.f;
      const uint4 v0 = *reinterpret_cast<const uint4*>(hsC + (size_t)s0 * 8 + half * 4);
      const uint4 v1 = *reinterpret_cast<const uint4*>(hsC + (size_t)s1 * 8 + half * 4);
#pragma unroll
      for (int q = 0; q < 4; ++q) {
        const float2 a0 = unpack_f16x2((&v0.x)[q]);
        const float2 a1 = unpack_f16x2((&v1.x)[q]);
        acc[q * 2]     = fmaf(a0.x, w0, acc[q * 2]);
        acc[q * 2 + 1] = fmaf(a0.y, w0, acc[q * 2 + 1]);
        acc[q * 2]     = fmaf(a1.x, w1, acc[q * 2]);
        acc[q * 2 + 1] = fmaf(a1.y, w1, acc[q * 2 + 1]);
      }
    }
    // reduce across 8 slot-lanes (lane bits 1..3; stays inside the 16-lane group)
#pragma unroll
    for (int j = 0; j < 8; ++j) {
      acc[j] += __shfl_xor(acc[j], 2);
      acc[j] += __shfl_xor(acc[j], 4);
      acc[j] += __shfl_xor(acc[j], 8);
    }
    if (il < 2) {   // lanes (slot 0, half 0/1) hold the 16-col result
      const float ndv = nd[d];
      const int c0 = p * 16 + half * 8;
      const float4 ca0 = *reinterpret_cast<const float4*>(CA + c0);
      const float4 ca1 = *reinterpret_cast<const float4*>(CA + c0 + 4);
      const float4 cb0 = *reinterpret_cast<const float4*>(CB + c0);
      const float4 cb1 = *reinterpret_cast<const float4*>(CB + c0 + 4);
      float rv[8];
      rv[0] = acc[0] * ndv * ca0.x + cb0.x;
      rv[1] = acc[1] * ndv * ca0.y + cb0.y;
      rv[2] = acc[2] * ndv * ca0.z + cb0.z;
      rv[3] = acc[3] * ndv * ca0.w + cb0.w;
      rv[4] = acc[4] * ndv * ca1.x + cb1.x;
      rv[5] = acc[5] * ndv * ca1.y + cb1.y;
      rv[6] = acc[6] * ndv * ca1.z + cb1.z;
      rv[7] = acc[7] * ndv * ca1.w + cb1.w;
      if (!last) {
        const float s = ns[d];
#pragma unroll
        for (int j = 0; j < 8; ++j) rv[j] = fmaxf(rv[j], 0.f) * s;
        uint4 u;
        u.x = pack_f16x2(rv[0], rv[1]);
        u.y = pack_f16x2(rv[2], rv[3]);
        u.z = pack_f16x2(rv[4], rv[5]);
        u.w = pack_f16x2(rv[6], rv[7]);
        *reinterpret_cast<uint4*>(hnext + ((size_t)p * N + d) * 8 + half * 4) = u;
      } else {
        *reinterpret_cast<float4*>(outf + (size_t)d * D + c0) =
            make_float4(rv[0], rv[1], rv[2], rv[3]);
        *reinterpret_cast<float4*>(outf + (size_t)d * D + c0 + 4) =
            make_float4(rv[4], rv[5], rv[6], rv[7]);
      }
    }
  }
}

// ---------------- launch ----------------

extern "C" void kernel_launch(void* const* d_in, const int* in_sizes, int n_in,
                              void* d_out, int out_size, void* d_ws, size_t ws_size,
                              hipStream_t stream) {
  const float* x = (const float*)d_in[0];
  const int* esrc = (const int*)d_in[1];
  const int* edst = (const int*)d_in[2];
  const float* W0 = (const float*)d_in[3];
  const float* b0 = (const float*)d_in[4];
  const float* W1 = (const float*)d_in[5];
  const float* b1 = (const float*)d_in[6];
  const float* W2 = (const float*)d_in[7];
  const float* b2 = (const float*)d_in[8];
  const float* g0 = (const float*)d_in[9];
  const float* be0 = (const float*)d_in[10];
  const float* m0 = (const float*)d_in[11];
  const float* v0 = (const float*)d_in[12];
  const float* g1 = (const float*)d_in[13];
  const float* be1 = (const float*)d_in[14];
  const float* m1 = (const float*)d_in[15];
  const float* v1 = (const float*)d_in[16];
  const int N = in_sizes[0] / D;
  const int E = in_sizes[1];

  const int SB = (E + NSL - 1) / NSL;
  const uint Msb = (uint)(((1ULL << 40) + (unsigned long long)SB - 1) / (unsigned long long)SB);

  char* p = (char*)d_ws;
  auto carve = [&](size_t bytes) {
    char* r = p;
    p += (bytes + 255) & ~(size_t)255;
    return (void*)r;
  };
  uint* hsA = (uint*)carve((size_t)N * 64 * 4);            // chunk-major f16 ping (ws)
  ushort* Wt = (ushort*)carve((size_t)3 * D * D * 2);
  float* CA = (float*)carve((size_t)3 * D * 4);
  float* CB = (float*)carve((size_t)3 * D * 4);
  float* ns = (float*)carve((size_t)N * 4);
  float* nd = (float*)carve((size_t)N * 4);
  uint* pd = (uint*)carve((size_t)NSL * PBU * 4);
  uint* ps = (uint*)carve((size_t)NSL * PBU * 4);
  uchar* rank8 = (uchar*)carve((size_t)E);
  int* totd = (int*)carve((size_t)N * 4);
  int* rofs = (int*)carve((size_t)(N + 1) * 4);
  const int nch = (N + 1023) / 1024;
  int* csum = (int*)carve((size_t)nch * 4);
  int* ticket = (int*)carve(256);
  int* csr = (int*)carve((size_t)E * 4);
  uint* hsB = (uint*)d_out;  // chunk-major f16 pong in d_out (fp32 out rewrites all later)

  hipMemsetAsync(ticket, 0, 4, stream);
  k_build1<<<113, 1024, 0, stream>>>(esrc, edst, W0, W1, W2, b0, b1, b2,
                                     g0, be0, m0, v0, g1, be1, m1, v1,
                                     pd, ps, rank8, Wt, CA, CB, E, SB);
  k_build2s<<<nch, 256, 0, stream>>>(pd, ps, totd, ns, nd, csum, rofs, ticket, N, nch);
  k_scan_final<<<nch, 256, 0, stream>>>(totd, csum, rofs, N);

  const int gb = (N + 127) / 128;
  const int scb = (E + 255) / 256;
  const int RB = 8;                      // 128 rows per spmm block
  const int spb = 8 * ((N + 16 * RB - 1) / (16 * RB));
  // layer-0 GEMM (f32 input, chunk-major out) + scatter merged
  k_sg<<<gb + scb, 256, 0, stream>>>(x, Wt, ns, (ushort*)hsA, esrc, edst, rank8, pd, rofs,
                                     csr, N, E, Msb, gb);
  // layer 0 spmm (col-sliced) -> hsB
  k_spmmc<<<spb, 256, 0, stream>>>(hsA, csr, rofs, nd, ns, CA, CB, nullptr, hsB, N, RB, 0);
  // layer 1 gemm -> hsA
  k_gemm16<<<gb, 256, 0, stream>>>((const ushort*)hsB, Wt + 16384, (ushort*)hsA, N);
  // layer 1 spmm -> hsB
  k_spmmc<<<spb, 256, 0, stream>>>(hsA, csr, rofs, nd, ns, CA + D, CB + D, nullptr, hsB, N,
                                   RB, 0);
  // layer 2 gemm -> hsA
  k_gemm16<<<gb, 256, 0, stream>>>((const ushort*)hsB, Wt + 32768, (ushort*)hsA, N);
  // layer 2 spmm (final) -> fp32 d_out
  k_spmmc<<<spb, 256, 0, stream>>>(hsA, csr, rofs, nd, ns, CA + 2 * D, CB + 2 * D,
                                   (float*)d_out, nullptr, N, RB, 1);
}

// Round 15
// 282.955 us; speedup vs baseline: 1.2365x; 1.2365x over previous
//
#include <hip/hip_runtime.h>
#include <hip/hip_fp16.h>
#include <math.h>

#define D 128
#define NSL 32          // edge slices
#define PBU 25088       // packed u8 counters (uints) -> supports N <= 100352

typedef _Float16 half8 __attribute__((ext_vector_type(8)));
typedef float f32x4 __attribute__((ext_vector_type(4)));

__device__ inline uint pack_f16x2(float a, float b) {
  __half2 h = __floats2half2_rn(a, b);
  return *reinterpret_cast<uint*>(&h);
}
__device__ inline float2 unpack_f16x2(uint p) {
  __half2 h = *reinterpret_cast<__half2*>(&p);
  return __half22float2(h);
}
__device__ inline uint mdiv40(uint x, uint M) {  // x / d with M = ceil(2^40/d)
  return (uint)(((unsigned long long)x * M) >> 40);
}

// ---------------- build1: fused {dst-hist+rank, src-hist, Wt transpose, CA/CB} ----------

__global__ __launch_bounds__(1024) void k_build1(const int* __restrict__ esrc,
                                                 const int* __restrict__ edst,
                                                 const float* __restrict__ W0,
                                                 const float* __restrict__ W1,
                                                 const float* __restrict__ W2,
                                                 const float* __restrict__ b0,
                                                 const float* __restrict__ b1,
                                                 const float* __restrict__ b2,
                                                 const float* __restrict__ g0,
                                                 const float* __restrict__ be0,
                                                 const float* __restrict__ mu0,
                                                 const float* __restrict__ vr0,
                                                 const float* __restrict__ g1,
                                                 const float* __restrict__ be1,
                                                 const float* __restrict__ mu1,
                                                 const float* __restrict__ vr1,
                                                 uint* __restrict__ pd,
                                                 uint* __restrict__ ps,
                                                 uchar* __restrict__ rank8,
                                                 ushort* __restrict__ Wt,
                                                 float* __restrict__ CA,
                                                 float* __restrict__ CB,
                                                 int E, int SB) {
  __shared__ uint h[PBU];   // ~98 KB static LDS (hist blocks only)
  const int b = blockIdx.x;
  const int t = threadIdx.x;
  if (b < 32) {             // ---- dst histogram + rank record
    for (int j = t; j < PBU; j += 1024) h[j] = 0u;
    __syncthreads();
    const int i0 = b * SB, i1 = min(i0 + SB, E);
    for (int i = i0 + t; i < i1; i += 1024) {
      const int d = edst[i];
      const uint sh = (uint)(d & 3) * 8u;
      const uint old = atomicAdd(&h[d >> 2], 1u << sh);
      rank8[i] = (uchar)((old >> sh) & 0xffu);
    }
    __syncthreads();
    uint* p = pd + (size_t)b * PBU;
    for (int j = t; j < PBU; j += 1024) p[j] = h[j];
  } else if (b < 64) {      // ---- src histogram (counts only)
    const int sl = b - 32;
    for (int j = t; j < PBU; j += 1024) h[j] = 0u;
    __syncthreads();
    const int i0 = sl * SB, i1 = min(i0 + SB, E);
    for (int i = i0 + t; i < i1; i += 1024) {
      const int s = esrc[i];
      atomicAdd(&h[s >> 2], 1u << ((uint)(s & 3) * 8u));
    }
    __syncthreads();
    uint* p = ps + (size_t)sl * PBU;
    for (int j = t; j < PBU; j += 1024) p[j] = h[j];
  } else if (b < 112) {     // ---- Wt[l][n][k] = f16(W_l[k][n])
    const int li = (b - 64) * 1024 + t;   // 0..49151
    const int l = li >> 14;
    const int i = li & 16383;
    const int n = i >> 7, k = i & 127;
    const float* W = (l == 0) ? W0 : ((l == 1) ? W1 : W2);
    Wt[li] = __half_as_ushort(__float2half_rn(W[k * D + n]));
  } else if (t < D) {       // ---- CA/CB fold bias+BN
    const int c = t;
    float A0 = g0[c] * rsqrtf(vr0[c] + 1e-5f);
    CA[c] = A0;
    CB[c] = (b0[c] - mu0[c]) * A0 + be0[c];
    float A1 = g1[c] * rsqrtf(vr1[c] + 1e-5f);
    CA[D + c] = A1;
    CB[D + c] = (b1[c] - mu1[c]) * A1 + be1[c];
    CA[2 * D + c] = 1.f;
    CB[2 * D + c] = b2[c];
  }
}

// ---- build2s: reduceN + chunk sum; LAST block serial-scans chunk sums ----

__global__ __launch_bounds__(256) void k_build2s(uint* __restrict__ pd,
                                                 const uint* __restrict__ ps,
                                                 int* __restrict__ totd,
                                                 float* __restrict__ ns,
                                                 float* __restrict__ nd,
                                                 int* __restrict__ csum,
                                                 int* __restrict__ rofs,
                                                 int* __restrict__ ticket,
                                                 int N, int nch) {
  __shared__ int sd[256];
  __shared__ int lastf;
  const int t = threadIdx.x;
  const int j = blockIdx.x * 256 + t;    // packed uint index (4 nodes), j < PBU
  const int n0 = j * 4;
  uint r0 = 0, r1 = 0, r2 = 0, r3 = 0;
  uint s0 = 0, s1 = 0, s2 = 0, s3 = 0;
#pragma unroll
  for (int sl = 0; sl < NSL; ++sl) {
    const uint v = pd[(size_t)sl * PBU + j];
    pd[(size_t)sl * PBU + j] = r0 | (r1 << 8) | (r2 << 16) | (r3 << 24);
    r0 += v & 0xffu; r1 += (v >> 8) & 0xffu; r2 += (v >> 16) & 0xffu; r3 += (v >> 24) & 0xffu;
    const uint w = ps[(size_t)sl * PBU + j];
    s0 += w & 0xffu; s1 += (w >> 8) & 0xffu; s2 += (w >> 16) & 0xffu; s3 += (w >> 24) & 0xffu;
  }
  const uint rr[4] = {r0, r1, r2, r3};
  const uint ss[4] = {s0, s1, s2, s3};
  int tot = 0;
#pragma unroll
  for (int k = 0; k < 4; ++k) {
    if (n0 + k < N) {
      totd[n0 + k] = (int)rr[k];
      nd[n0 + k] = rsqrtf((float)max(rr[k], 1u));
      ns[n0 + k] = rsqrtf((float)max(ss[k], 1u));
      tot += (int)rr[k];
    }
  }
  sd[t] = tot; __syncthreads();
  for (int off = 128; off > 0; off >>= 1) {
    if (t < off) sd[t] += sd[t + off];
    __syncthreads();
  }
  if (t == 0) {
    csum[blockIdx.x] = sd[0];
    __threadfence();
    lastf = (atomicAdd(&ticket[0], 1) == nch - 1) ? 1 : 0;
  }
  __syncthreads();
  if (lastf && t < 64) {
    __threadfence();
    int run = 0;
    for (int b0 = 0; b0 < nch; b0 += 64) {
      const int idx = b0 + t;
      int v = (idx < nch) ? __hip_atomic_load(&csum[idx], __ATOMIC_RELAXED,
                                              __HIP_MEMORY_SCOPE_AGENT) : 0;
      int sc = v;
#pragma unroll
      for (int off = 1; off < 64; off <<= 1) {
        int u = __shfl_up(sc, off);
        if (t >= off) sc += u;
      }
      if (idx < nch) csum[idx] = run + sc - v;
      run += __shfl(sc, 63);
    }
    if (t == 0) rofs[N] = run;
  }
}

// ---- scan_final2: per-node rofs + 64-bin degree hist/rank; last block scans (blk,bin) ----

__global__ __launch_bounds__(256) void k_scan_final2(const int* __restrict__ totd,
                                                     const int* __restrict__ csum,
                                                     int* __restrict__ rofs,
                                                     ushort* __restrict__ drank,
                                                     uint* __restrict__ phist,
                                                     int* __restrict__ ticket,
                                                     int n, int nch) {
  __shared__ int sd[256];
  __shared__ uint hist[64];
  __shared__ int lastf;
  const int b = blockIdx.x, t = threadIdx.x;
  const int base = b * 1024 + t * 4;
  int v[4]; int s = 0;
#pragma unroll
  for (int i = 0; i < 4; ++i) { v[i] = (base + i < n) ? totd[base + i] : 0; s += v[i]; }
  sd[t] = s; __syncthreads();
  for (int off = 1; off < 256; off <<= 1) {
    int x = (t >= off) ? sd[t - off] : 0;
    __syncthreads();
    sd[t] += x;
    __syncthreads();
  }
  int o = sd[t] - s + csum[b];
#pragma unroll
  for (int i = 0; i < 4; ++i) {
    if (base + i < n) { rofs[base + i] = o; o += v[i]; }
  }
  // degree hist + per-node rank
  if (t < 64) hist[t] = 0u;
  __syncthreads();
  uint rk[4];
#pragma unroll
  for (int i = 0; i < 4; ++i) {
    if (base + i < n) {
      const int bin = min(v[i], 63);
      rk[i] = atomicAdd(&hist[bin], 1u);
    }
  }
#pragma unroll
  for (int i = 0; i < 4; ++i)
    if (base + i < n) drank[base + i] = (ushort)rk[i];
  __syncthreads();
  if (t < 64) phist[b * 64 + t] = hist[t];
  if (t == 0) {
    __threadfence();
    lastf = (atomicAdd(&ticket[1], 1) == nch - 1) ? 1 : 0;
  }
  __syncthreads();
  if (lastf && t < 64) {   // wave 0: exclusive scan over bins (outer) x blocks (inner)
    __threadfence();
    uint sumb = 0;
    for (int blk = 0; blk < nch; ++blk)
      sumb += __hip_atomic_load(&phist[blk * 64 + t], __ATOMIC_RELAXED,
                                __HIP_MEMORY_SCOPE_AGENT);
    uint sc = sumb;
#pragma unroll
    for (int off = 1; off < 64; off <<= 1) {
      uint u = __shfl_up(sc, off);
      if (t >= off) sc += u;
    }
    uint run = sc - sumb;   // exclusive base of bin t
    for (int blk = 0; blk < nch; ++blk) {
      const uint vv = __hip_atomic_load(&phist[blk * 64 + t], __ATOMIC_RELAXED,
                                        __HIP_MEMORY_SCOPE_AGENT);
      phist[blk * 64 + t] = run;
      run += vv;
    }
  }
}

// ---- permscat: build perm/inv + permuted nsS/ndS/begS/degS ----

__global__ void k_permscat(const int* __restrict__ totd, const ushort* __restrict__ drank,
                           const uint* __restrict__ pbase, const float* __restrict__ ns,
                           const float* __restrict__ nd, const int* __restrict__ rofs,
                           int* __restrict__ perm, int* __restrict__ inv,
                           float* __restrict__ nsS, float* __restrict__ ndS,
                           int* __restrict__ begS, int* __restrict__ degS, int N) {
  const int nIdx = blockIdx.x * 256 + threadIdx.x;
  if (nIdx >= N) return;
  const int deg = totd[nIdx];
  const int bin = min(deg, 63);
  const int blk = nIdx >> 10;
  const int pos = (int)pbase[blk * 64 + bin] + (int)drank[nIdx];
  perm[pos] = nIdx;
  inv[nIdx] = pos;
  nsS[pos] = ns[nIdx];
  ndS[pos] = nd[nIdx];
  begS[pos] = rofs[nIdx];
  degS[pos] = deg;
}

// ---- sg: merged {layer-0 GEMM in SORTED space (X row-gather via perm)} + {scatter} ----

__global__ __launch_bounds__(256) void k_sg(const float* __restrict__ X,
                                            const ushort* __restrict__ Wt,
                                            const float* __restrict__ nsS,
                                            const int* __restrict__ perm,
                                            const int* __restrict__ inv,
                                            ushort* __restrict__ out,
                                            const int* __restrict__ esrc,
                                            const int* __restrict__ edst,
                                            const uchar* __restrict__ rank8,
                                            const uint* __restrict__ pd,
                                            const int* __restrict__ rofs,
                                            int* __restrict__ csr,
                                            int M, int E, uint Msb, int GB) {
  if ((int)blockIdx.x >= GB) {   // ---- scatter part (csr content remapped to sorted space)
    const int i = ((int)blockIdx.x - GB) * 256 + threadIdx.x;
    if (i < E) {
      const int d = edst[i];
      const uint sl = mdiv40((uint)i, Msb);
      const uint pk = pd[(size_t)sl * PBU + (d >> 2)];
      const uint pfx = (pk >> ((uint)(d & 3) * 8u)) & 0xffu;
      csr[rofs[d] + (int)pfx + (int)rank8[i]] = inv[esrc[i]];
    }
    return;
  }
  // ---- gemm32 part: sorted row r reads X[perm[r]] * nsS[r]
  const int lane = threadIdx.x & 63;
  const int wv = threadIdx.x >> 6;
  const int m0 = (blockIdx.x * 4 + wv) * 32;
  if (m0 >= M) return;
  const int lr = lane & 15;
  const int kg = (lane >> 4) * 8;

  half8 hf[2][4];
  const half8 hz = {};
#pragma unroll
  for (int mt = 0; mt < 2; ++mt) {
    const int row = m0 + mt * 16 + lr;
    if (row < M) {
      const int orig = perm[row];
      const float s = nsS[row];
#pragma unroll
      for (int kt = 0; kt < 4; ++kt) {
        const float4 a = *reinterpret_cast<const float4*>(X + (size_t)orig * D + kt * 32 + kg);
        const float4 b = *reinterpret_cast<const float4*>(X + (size_t)orig * D + kt * 32 + kg + 4);
        half8 hv;
        hv[0] = (_Float16)(a.x * s); hv[1] = (_Float16)(a.y * s);
        hv[2] = (_Float16)(a.z * s); hv[3] = (_Float16)(a.w * s);
        hv[4] = (_Float16)(b.x * s); hv[5] = (_Float16)(b.y * s);
        hv[6] = (_Float16)(b.z * s); hv[7] = (_Float16)(b.w * s);
        hf[mt][kt] = hv;
      }
    } else {
#pragma unroll
      for (int kt = 0; kt < 4; ++kt) hf[mt][kt] = hz;
    }
  }

  f32x4 acc[8][2];
#pragma unroll
  for (int nt = 0; nt < 8; ++nt) { acc[nt][0] = (f32x4)(0.f); acc[nt][1] = (f32x4)(0.f); }

#pragma unroll
  for (int nt = 0; nt < 8; ++nt) {
    const ushort* wb = Wt + (size_t)(nt * 16 + lr) * D + kg;
#pragma unroll
    for (int kt = 0; kt < 4; ++kt) {
      half8 wf = *reinterpret_cast<const half8*>(wb + kt * 32);
      acc[nt][0] = __builtin_amdgcn_mfma_f32_16x16x32_f16(wf, hf[0][kt], acc[nt][0], 0, 0, 0);
      acc[nt][1] = __builtin_amdgcn_mfma_f32_16x16x32_f16(wf, hf[1][kt], acc[nt][1], 0, 0, 0);
    }
  }

  const int mo = lane & 15;
  const int no = (lane >> 4) * 4;
#pragma unroll
  for (int mt = 0; mt < 2; ++mt) {
    const int row = m0 + mt * 16 + mo;
    if (row < M) {
#pragma unroll
      for (int nt = 0; nt < 8; ++nt) {
        uint2 u;
        u.x = pack_f16x2(acc[nt][mt][0], acc[nt][mt][1]);
        u.y = pack_f16x2(acc[nt][mt][2], acc[nt][mt][3]);
        *reinterpret_cast<uint2*>(out + (size_t)row * D + nt * 16 + no) = u;
      }
    }
  }
}

// ---- k_spgm: FUSED spmm + next-layer GEMM, all in sorted space. Block = 128 rows. ----

__global__ __launch_bounds__(256) void k_spgm(const uint* __restrict__ hs,
                                              const int* __restrict__ csr,
                                              const int* __restrict__ begS,
                                              const int* __restrict__ degS,
                                              const float* __restrict__ ndS,
                                              const float* __restrict__ nsS,
                                              const float* __restrict__ CA,
                                              const float* __restrict__ CB,
                                              const ushort* __restrict__ Wt,
                                              ushort* __restrict__ out, int N) {
  __shared__ ushort A[128 * 136];   // 34816 B; row stride 272 B (16B-aligned)
  const int t = threadIdx.x;
  const int lane = t & 63;
  const int c16 = lane & 15;
  const int gb = lane & ~15;
  const int g = t >> 4;            // group 0..15
  const int rbase = blockIdx.x * 128;

  // ---- Phase A: spmm into LDS (rows 16r+g: wave's groups get consecutive sorted rows) ----
#pragma unroll 1
  for (int r = 0; r < 8; ++r) {
    const int rl = r * 16 + g;
    const int d = rbase + rl;
    uint4 uo = make_uint4(0u, 0u, 0u, 0u);
    if (d < N) {
      const int beg = begS[d];
      const int end = beg + degS[d];
      float acc[8];
#pragma unroll
      for (int j = 0; j < 8; ++j) acc[j] = 0.f;
      for (int eb = beg; eb < end; eb += 16) {
        const int len = min(16, end - eb);
        const int idx = csr[min(eb + c16, end - 1)];
#pragma unroll 1
        for (int j = 0; j < len; j += 4) {
          const int l1 = min(j + 1, len - 1), l2 = min(j + 2, len - 1), l3 = min(j + 3, len - 1);
          const int s0 = __shfl(idx, gb + j);
          const int s1 = __shfl(idx, gb + l1);
          const int s2 = __shfl(idx, gb + l2);
          const int s3 = __shfl(idx, gb + l3);
          const float w1 = (j + 1 < len) ? 1.f : 0.f;
          const float w2 = (j + 2 < len) ? 1.f : 0.f;
          const float w3 = (j + 3 < len) ? 1.f : 0.f;
          const uint4 v0 = *reinterpret_cast<const uint4*>(hs + (size_t)s0 * 64 + c16 * 4);
          const uint4 v1 = *reinterpret_cast<const uint4*>(hs + (size_t)s1 * 64 + c16 * 4);
          const uint4 v2 = *reinterpret_cast<const uint4*>(hs + (size_t)s2 * 64 + c16 * 4);
          const uint4 v3 = *reinterpret_cast<const uint4*>(hs + (size_t)s3 * 64 + c16 * 4);
#pragma unroll
          for (int q = 0; q < 4; ++q) {
            const float2 a0 = unpack_f16x2((&v0.x)[q]);
            const float2 a1 = unpack_f16x2((&v1.x)[q]);
            const float2 a2 = unpack_f16x2((&v2.x)[q]);
            const float2 a3 = unpack_f16x2((&v3.x)[q]);
            acc[q * 2]     += a0.x;
            acc[q * 2 + 1] += a0.y;
            acc[q * 2]     = fmaf(a1.x, w1, acc[q * 2]);
            acc[q * 2 + 1] = fmaf(a1.y, w1, acc[q * 2 + 1]);
            acc[q * 2]     = fmaf(a2.x, w2, acc[q * 2]);
            acc[q * 2 + 1] = fmaf(a2.y, w2, acc[q * 2 + 1]);
            acc[q * 2]     = fmaf(a3.x, w3, acc[q * 2]);
            acc[q * 2 + 1] = fmaf(a3.y, w3, acc[q * 2 + 1]);
          }
        }
      }
      const float ndv = ndS[d];
      const float s = nsS[d];
      const float4 ca0 = *reinterpret_cast<const float4*>(CA + c16 * 8);
      const float4 ca1 = *reinterpret_cast<const float4*>(CA + c16 * 8 + 4);
      const float4 cb0 = *reinterpret_cast<const float4*>(CB + c16 * 8);
      const float4 cb1 = *reinterpret_cast<const float4*>(CB + c16 * 8 + 4);
      float rv[8];
      rv[0] = acc[0] * ndv * ca0.x + cb0.x;
      rv[1] = acc[1] * ndv * ca0.y + cb0.y;
      rv[2] = acc[2] * ndv * ca0.z + cb0.z;
      rv[3] = acc[3] * ndv * ca0.w + cb0.w;
      rv[4] = acc[4] * ndv * ca1.x + cb1.x;
      rv[5] = acc[5] * ndv * ca1.y + cb1.y;
      rv[6] = acc[6] * ndv * ca1.z + cb1.z;
      rv[7] = acc[7] * ndv * ca1.w + cb1.w;
#pragma unroll
      for (int j = 0; j < 8; ++j) rv[j] = fmaxf(rv[j], 0.f) * s;
      uo.x = pack_f16x2(rv[0], rv[1]);
      uo.y = pack_f16x2(rv[2], rv[3]);
      uo.z = pack_f16x2(rv[4], rv[5]);
      uo.w = pack_f16x2(rv[6], rv[7]);
    }
    *reinterpret_cast<uint4*>(&A[rl * 136 + c16 * 8]) = uo;
  }
  __syncthreads();

  // ---- Phase B: GEMM from LDS (dense sorted rows out) ----
  const int w = t >> 6;
  const int m0l = w * 32;
  const int m0 = rbase + m0l;
  if (m0 >= N) return;
  const int lr = lane & 15;
  const int kg = (lane >> 4) * 8;
  half8 hf[2][4];
#pragma unroll
  for (int mt = 0; mt < 2; ++mt) {
    const int row_l = m0l + mt * 16 + lr;
#pragma unroll
    for (int kt = 0; kt < 4; ++kt)
      hf[mt][kt] = *reinterpret_cast<const half8*>(&A[row_l * 136 + kt * 32 + kg]);
  }
  const int no = (lane >> 4) * 4;
#pragma unroll
  for (int nt = 0; nt < 8; ++nt) {
    f32x4 a0 = (f32x4)(0.f), a1 = (f32x4)(0.f);
    const ushort* wb = Wt + (size_t)(nt * 16 + lr) * D + kg;
#pragma unroll
    for (int kt = 0; kt < 4; ++kt) {
      half8 wf = *reinterpret_cast<const half8*>(wb + kt * 32);
      a0 = __builtin_amdgcn_mfma_f32_16x16x32_f16(wf, hf[0][kt], a0, 0, 0, 0);
      a1 = __builtin_amdgcn_mfma_f32_16x16x32_f16(wf, hf[1][kt], a1, 0, 0, 0);
    }
    const int r0 = m0 + lr, r1 = m0 + 16 + lr;
    if (r0 < N) {
      uint2 u; u.x = pack_f16x2(a0[0], a0[1]); u.y = pack_f16x2(a0[2], a0[3]);
      *reinterpret_cast<uint2*>(out + (size_t)r0 * D + nt * 16 + no) = u;
    }
    if (r1 < N) {
      uint2 u; u.x = pack_f16x2(a1[0], a1[1]); u.y = pack_f16x2(a1[2], a1[3]);
      *reinterpret_cast<uint2*>(out + (size_t)r1 * D + nt * 16 + no) = u;
    }
  }
}

// ---------------- SpMM (standalone final layer, sorted space -> fp32 out via perm) --------

__global__ __launch_bounds__(256) void k_spmm16(const uint* __restrict__ hs,
                                                const int* __restrict__ csr,
                                                const int* __restrict__ begS,
                                                const int* __restrict__ degS,
                                                const float* __restrict__ ndS,
                                                const int* __restrict__ perm,
                                                const float* __restrict__ CA,
                                                const float* __restrict__ CB,
                                                float* __restrict__ outf, int N) {
  const int t = threadIdx.x;
  const int lane = t & 63;
  const int c16 = lane & 15;
  const int gb = lane & ~15;
  const int d = blockIdx.x * 16 + (t >> 4);
  if (d >= N) return;
  const int beg = begS[d];
  const int end = beg + degS[d];

  float acc[8];
#pragma unroll
  for (int j = 0; j < 8; ++j) acc[j] = 0.f;

  for (int base = beg; base < end; base += 16) {
    const int len = min(16, end - base);
    const int idx = csr[min(base + c16, end - 1)];
#pragma unroll 1
    for (int j = 0; j < len; j += 4) {
      const int l1 = min(j + 1, len - 1), l2 = min(j + 2, len - 1), l3 = min(j + 3, len - 1);
      const int s0 = __shfl(idx, gb + j);
      const int s1 = __shfl(idx, gb + l1);
      const int s2 = __shfl(idx, gb + l2);
      const int s3 = __shfl(idx, gb + l3);
      const float w1 = (j + 1 < len) ? 1.f : 0.f;
      const float w2 = (j + 2 < len) ? 1.f : 0.f;
      const float w3 = (j + 3 < len) ? 1.f : 0.f;
      const uint4 v0 = *reinterpret_cast<const uint4*>(hs + (size_t)s0 * 64 + c16 * 4);
      const uint4 v1 = *reinterpret_cast<const uint4*>(hs + (size_t)s1 * 64 + c16 * 4);
      const uint4 v2 = *reinterpret_cast<const uint4*>(hs + (size_t)s2 * 64 + c16 * 4);
      const uint4 v3 = *reinterpret_cast<const uint4*>(hs + (size_t)s3 * 64 + c16 * 4);
#pragma unroll
      for (int q = 0; q < 4; ++q) {
        const float2 a0 = unpack_f16x2((&v0.x)[q]);
        const float2 a1 = unpack_f16x2((&v1.x)[q]);
        const float2 a2 = unpack_f16x2((&v2.x)[q]);
        const float2 a3 = unpack_f16x2((&v3.x)[q]);
        acc[q * 2]     += a0.x;
        acc[q * 2 + 1] += a0.y;
        acc[q * 2]     = fmaf(a1.x, w1, acc[q * 2]);
        acc[q * 2 + 1] = fmaf(a1.y, w1, acc[q * 2 + 1]);
        acc[q * 2]     = fmaf(a2.x, w2, acc[q * 2]);
        acc[q * 2 + 1] = fmaf(a2.y, w2, acc[q * 2 + 1]);
        acc[q * 2]     = fmaf(a3.x, w3, acc[q * 2]);
        acc[q * 2 + 1] = fmaf(a3.y, w3, acc[q * 2 + 1]);
      }
    }
  }

  const float ndv = ndS[d];
  const int orig = perm[d];
  const float4 ca0 = *reinterpret_cast<const float4*>(CA + c16 * 8);
  const float4 ca1 = *reinterpret_cast<const float4*>(CA + c16 * 8 + 4);
  const float4 cb0 = *reinterpret_cast<const float4*>(CB + c16 * 8);
  const float4 cb1 = *reinterpret_cast<const float4*>(CB + c16 * 8 + 4);
  float4 o0, o1;
  o0.x = acc[0] * ndv * ca0.x + cb0.x;
  o0.y = acc[1] * ndv * ca0.y + cb0.y;
  o0.z = acc[2] * ndv * ca0.z + cb0.z;
  o0.w = acc[3] * ndv * ca0.w + cb0.w;
  o1.x = acc[4] * ndv * ca1.x + cb1.x;
  o1.y = acc[5] * ndv * ca1.y + cb1.y;
  o1.z = acc[6] * ndv * ca1.z + cb1.z;
  o1.w = acc[7] * ndv * ca1.w + cb1.w;
  *reinterpret_cast<float4*>(outf + (size_t)orig * D + c16 * 8) = o0;
  *reinterpret_cast<float4*>(outf + (size_t)orig * D + c16 * 8 + 4) = o1;
}

// ---------------- launch ----------------

extern "C" void kernel_launch(void* const* d_in, const int* in_sizes, int n_in,
                              void* d_out, int out_size, void* d_ws, size_t ws_size,
                              hipStream_t stream) {
  const float* x = (const float*)d_in[0];
  const int* esrc = (const int*)d_in[1];
  const int* edst = (const int*)d_in[2];
  const float* W0 = (const float*)d_in[3];
  const float* b0 = (const float*)d_in[4];
  const float* W1 = (const float*)d_in[5];
  const float* b1 = (const float*)d_in[6];
  const float* W2 = (const float*)d_in[7];
  const float* b2 = (const float*)d_in[8];
  const float* g0 = (const float*)d_in[9];
  const float* be0 = (const float*)d_in[10];
  const float* m0 = (const float*)d_in[11];
  const float* v0 = (const float*)d_in[12];
  const float* g1 = (const float*)d_in[13];
  const float* be1 = (const float*)d_in[14];
  const float* m1 = (const float*)d_in[15];
  const float* v1 = (const float*)d_in[16];
  const int N = in_sizes[0] / D;
  const int E = in_sizes[1];

  const int SB = (E + NSL - 1) / NSL;
  const uint Msb = (uint)(((1ULL << 40) + (unsigned long long)SB - 1) / (unsigned long long)SB);

  char* p = (char*)d_ws;
  auto carve = [&](size_t bytes) {
    char* r = p;
    p += (bytes + 255) & ~(size_t)255;
    return (void*)r;
  };
  uint* hsA = (uint*)carve((size_t)N * 64 * 4);            // sorted-space f16 ping (ws)
  ushort* Wt = (ushort*)carve((size_t)3 * D * D * 2);
  float* CA = (float*)carve((size_t)3 * D * 4);
  float* CB = (float*)carve((size_t)3 * D * 4);
  float* ns = (float*)carve((size_t)N * 4);
  float* nd = (float*)carve((size_t)N * 4);
  float* nsS = (float*)carve((size_t)N * 4);
  float* ndS = (float*)carve((size_t)N * 4);
  uint* pd = (uint*)carve((size_t)NSL * PBU * 4);
  uint* ps = (uint*)carve((size_t)NSL * PBU * 4);
  uchar* rank8 = (uchar*)carve((size_t)E);
  int* totd = (int*)carve((size_t)N * 4);
  int* rofs = (int*)carve((size_t)(N + 1) * 4);
  const int nch = (N + 1023) / 1024;
  int* csum = (int*)carve((size_t)nch * 4);
  int* ticket = (int*)carve(256);
  int* csr = (int*)carve((size_t)E * 4);
  ushort* drank = (ushort*)carve((size_t)N * 2);
  uint* phist = (uint*)carve((size_t)nch * 64 * 4);
  int* perm = (int*)carve((size_t)N * 4);
  int* inv = (int*)carve((size_t)N * 4);
  int* begS = (int*)carve((size_t)N * 4);
  int* degS = (int*)carve((size_t)N * 4);
  uint* hsB = (uint*)d_out;  // sorted-space f16 pong in d_out (fp32 out rewrites all later)

  hipMemsetAsync(ticket, 0, 8, stream);
  k_build1<<<113, 1024, 0, stream>>>(esrc, edst, W0, W1, W2, b0, b1, b2,
                                     g0, be0, m0, v0, g1, be1, m1, v1,
                                     pd, ps, rank8, Wt, CA, CB, E, SB);
  k_build2s<<<nch, 256, 0, stream>>>(pd, ps, totd, ns, nd, csum, rofs, ticket, N, nch);
  k_scan_final2<<<nch, 256, 0, stream>>>(totd, csum, rofs, drank, phist, ticket, N, nch);
  k_permscat<<<(N + 255) / 256, 256, 0, stream>>>(totd, drank, phist, ns, nd, rofs,
                                                  perm, inv, nsS, ndS, begS, degS, N);

  const int gb = (N + 127) / 128;
  const int scb = (E + 255) / 256;
  const int fb = (N + 127) / 128;
  const int sb = (N + 15) / 16;
  // layer-0 GEMM (sorted space) + scatter merged
  k_sg<<<gb + scb, 256, 0, stream>>>(x, Wt, nsS, perm, inv, (ushort*)hsA, esrc, edst,
                                     rank8, pd, rofs, csr, N, E, Msb, gb);
  // fused: spmm L0 + gemm L1 -> d_out f16
  k_spgm<<<fb, 256, 0, stream>>>(hsA, csr, begS, degS, ndS, nsS, CA, CB, Wt + 16384,
                                 (ushort*)hsB, N);
  // fused: spmm L1 + gemm L2 -> hsA
  k_spgm<<<fb, 256, 0, stream>>>(hsB, csr, begS, degS, ndS, nsS, CA + D, CB + D,
                                 Wt + 32768, (ushort*)hsA, N);
  // final spmm L2 -> fp32 out (original row order via perm)
  k_spmm16<<<sb, 256, 0, stream>>>(hsA, csr, begS, degS, ndS, perm, CA + 2 * D, CB + 2 * D,
                                   (float*)d_out, N);
}

// Round 16
// 260.087 us; speedup vs baseline: 1.3452x; 1.0879x over previous
//
#include <hip/hip_runtime.h>
#include <hip/hip_fp16.h>
#include <math.h>

#define D 128
#define NSL 32          // edge slices
#define PBU 25088       // packed u8 counters (uints) -> supports N <= 100352

typedef _Float16 half8 __attribute__((ext_vector_type(8)));
typedef float f32x4 __attribute__((ext_vector_type(4)));

__device__ inline uint pack_f16x2(float a, float b) {
  __half2 h = __floats2half2_rn(a, b);
  return *reinterpret_cast<uint*>(&h);
}
__device__ inline float2 unpack_f16x2(uint p) {
  __half2 h = *reinterpret_cast<__half2*>(&p);
  return __half22float2(h);
}

// ---------------- build1: fused {dst-hist+rank, src-hist, Wt transpose, CA/CB} ----------

__global__ __launch_bounds__(1024) void k_build1(const int* __restrict__ esrc,
                                                 const int* __restrict__ edst,
                                                 const float* __restrict__ W0,
                                                 const float* __restrict__ W1,
                                                 const float* __restrict__ W2,
                                                 const float* __restrict__ b0,
                                                 const float* __restrict__ b1,
                                                 const float* __restrict__ b2,
                                                 const float* __restrict__ g0,
                                                 const float* __restrict__ be0,
                                                 const float* __restrict__ mu0,
                                                 const float* __restrict__ vr0,
                                                 const float* __restrict__ g1,
                                                 const float* __restrict__ be1,
                                                 const float* __restrict__ mu1,
                                                 const float* __restrict__ vr1,
                                                 uint* __restrict__ pd,
                                                 uint* __restrict__ ps,
                                                 uchar* __restrict__ rank8,
                                                 ushort* __restrict__ Wt,
                                                 float* __restrict__ CA,
                                                 float* __restrict__ CB,
                                                 int E, int SB) {
  __shared__ uint h[PBU];   // ~98 KB static LDS (hist blocks only)
  const int b = blockIdx.x;
  const int t = threadIdx.x;
  if (b < 32) {             // ---- dst histogram + rank record
    for (int j = t; j < PBU; j += 1024) h[j] = 0u;
    __syncthreads();
    const int i0 = b * SB, i1 = min(i0 + SB, E);
    for (int i = i0 + t; i < i1; i += 1024) {
      const int d = edst[i];
      const uint sh = (uint)(d & 3) * 8u;
      const uint old = atomicAdd(&h[d >> 2], 1u << sh);
      rank8[i] = (uchar)((old >> sh) & 0xffu);
    }
    __syncthreads();
    uint* p = pd + (size_t)b * PBU;
    for (int j = t; j < PBU; j += 1024) p[j] = h[j];
  } else if (b < 64) {      // ---- src histogram (counts only)
    const int sl = b - 32;
    for (int j = t; j < PBU; j += 1024) h[j] = 0u;
    __syncthreads();
    const int i0 = sl * SB, i1 = min(i0 + SB, E);
    for (int i = i0 + t; i < i1; i += 1024) {
      const int s = esrc[i];
      atomicAdd(&h[s >> 2], 1u << ((uint)(s & 3) * 8u));
    }
    __syncthreads();
    uint* p = ps + (size_t)sl * PBU;
    for (int j = t; j < PBU; j += 1024) p[j] = h[j];
  } else if (b < 112) {     // ---- Wt[l][n][k] = f16(W_l[k][n])
    const int li = (b - 64) * 1024 + t;   // 0..49151
    const int l = li >> 14;
    const int i = li & 16383;
    const int n = i >> 7, k = i & 127;
    const float* W = (l == 0) ? W0 : ((l == 1) ? W1 : W2);
    Wt[li] = __half_as_ushort(__float2half_rn(W[k * D + n]));
  } else if (t < D) {       // ---- CA/CB fold bias+BN
    const int c = t;
    float A0 = g0[c] * rsqrtf(vr0[c] + 1e-5f);
    CA[c] = A0;
    CB[c] = (b0[c] - mu0[c]) * A0 + be0[c];
    float A1 = g1[c] * rsqrtf(vr1[c] + 1e-5f);
    CA[D + c] = A1;
    CB[D + c] = (b1[c] - mu1[c]) * A1 + be1[c];
    CA[2 * D + c] = 1.f;
    CB[2 * D + c] = b2[c];
  }
}

// ---- build2s: reduceN + chunk sum; LAST block serial-scans chunk sums ----

__global__ __launch_bounds__(256) void k_build2s(uint* __restrict__ pd,
                                                 const uint* __restrict__ ps,
                                                 int* __restrict__ totd,
                                                 float* __restrict__ ns,
                                                 float* __restrict__ nd,
                                                 int* __restrict__ csum,
                                                 int* __restrict__ rofs,
                                                 int* __restrict__ ticket,
                                                 int N, int nch) {
  __shared__ int sd[256];
  __shared__ int lastf;
  const int t = threadIdx.x;
  const int j = blockIdx.x * 256 + t;    // packed uint index (4 nodes), j < PBU
  const int n0 = j * 4;
  uint r0 = 0, r1 = 0, r2 = 0, r3 = 0;
  uint s0 = 0, s1 = 0, s2 = 0, s3 = 0;
#pragma unroll
  for (int sl = 0; sl < NSL; ++sl) {
    const uint v = pd[(size_t)sl * PBU + j];
    pd[(size_t)sl * PBU + j] = r0 | (r1 << 8) | (r2 << 16) | (r3 << 24);
    r0 += v & 0xffu; r1 += (v >> 8) & 0xffu; r2 += (v >> 16) & 0xffu; r3 += (v >> 24) & 0xffu;
    const uint w = ps[(size_t)sl * PBU + j];
    s0 += w & 0xffu; s1 += (w >> 8) & 0xffu; s2 += (w >> 16) & 0xffu; s3 += (w >> 24) & 0xffu;
  }
  const uint rr[4] = {r0, r1, r2, r3};
  const uint ss[4] = {s0, s1, s2, s3};
  int tot = 0;
#pragma unroll
  for (int k = 0; k < 4; ++k) {
    if (n0 + k < N) {
      totd[n0 + k] = (int)rr[k];
      nd[n0 + k] = rsqrtf((float)max(rr[k], 1u));
      ns[n0 + k] = rsqrtf((float)max(ss[k], 1u));
      tot += (int)rr[k];
    }
  }
  sd[t] = tot; __syncthreads();
  for (int off = 128; off > 0; off >>= 1) {
    if (t < off) sd[t] += sd[t + off];
    __syncthreads();
  }
  if (t == 0) {
    csum[blockIdx.x] = sd[0];
    __threadfence();
    lastf = (atomicAdd(ticket, 1) == nch - 1) ? 1 : 0;
  }
  __syncthreads();
  if (lastf && t < 64) {
    __threadfence();
    int run = 0;
    for (int b0 = 0; b0 < nch; b0 += 64) {
      const int idx = b0 + t;
      int v = (idx < nch) ? __hip_atomic_load(&csum[idx], __ATOMIC_RELAXED,
                                              __HIP_MEMORY_SCOPE_AGENT) : 0;
      int sc = v;
#pragma unroll
      for (int off = 1; off < 64; off <<= 1) {
        int u = __shfl_up(sc, off);
        if (t >= off) sc += u;
      }
      if (idx < nch) csum[idx] = run + sc - v;
      run += __shfl(sc, 63);
    }
    if (t == 0) rofs[N] = run;
  }
}

// ---------------- final per-node rofs scan ----------------

__global__ __launch_bounds__(256) void k_scan_final(const int* __restrict__ totd,
                                                    const int* __restrict__ csum,
                                                    int* __restrict__ rofs, int n) {
  __shared__ int sd[256];
  const int b = blockIdx.x, t = threadIdx.x;
  const int base = b * 1024 + t * 4;
  int v[4]; int s = 0;
#pragma unroll
  for (int i = 0; i < 4; ++i) { v[i] = (base + i < n) ? totd[base + i] : 0; s += v[i]; }
  sd[t] = s; __syncthreads();
  for (int off = 1; off < 256; off <<= 1) {
    int x = (t >= off) ? sd[t - off] : 0;
    __syncthreads();
    sd[t] += x;
    __syncthreads();
  }
  int o = sd[t] - s + csum[b];
#pragma unroll
  for (int i = 0; i < 4; ++i) {
    if (base + i < n) { rofs[base + i] = o; o += v[i]; }
  }
}

// ---- sg: merged {layer-0 GEMM (f32 input, ns folded)} + {(slice x chunk) scatter} ----
// Scatter block (sl, c): re-reads slice sl's edges coalesced (8 blocks share a slice ->
// L2/L3 hits), keeps d in chunk c, writes into chunk c's CONTIGUOUS csr segment
// (random within 512 KB -> lines coalesce in L2 before write-back).

__global__ __launch_bounds__(256) void k_sg(const float* __restrict__ X,
                                            const ushort* __restrict__ Wt,
                                            const float* __restrict__ ns,
                                            ushort* __restrict__ out,
                                            const int* __restrict__ esrc,
                                            const int* __restrict__ edst,
                                            const uchar* __restrict__ rank8,
                                            const uint* __restrict__ pd,
                                            const int* __restrict__ rofs,
                                            int* __restrict__ csr,
                                            int M, int E, int SB, int BPC, int GB) {
  if ((int)blockIdx.x >= GB) {   // ---- scatter part
    const int bb = (int)blockIdx.x - GB;   // 0..255
    const int sl = bb >> 3;
    const int c = bb & 7;
    const int c0 = c * BPC;
    const int c1 = min(c0 + BPC, M);
    const int i0 = sl * SB;                // SB multiple of 4
    const int i1 = min(i0 + SB, E);
    const uint* pdsl = pd + (size_t)sl * PBU;
    for (int vi = (i0 >> 2) + threadIdx.x; vi < ((i1 + 3) >> 2); vi += 256) {
      const int ib = vi << 2;
      int dv[4], sv[4];
      if (ib + 3 < i1) {
        const int4 d4 = reinterpret_cast<const int4*>(edst)[vi];
        const int4 s4 = reinterpret_cast<const int4*>(esrc)[vi];
        dv[0] = d4.x; dv[1] = d4.y; dv[2] = d4.z; dv[3] = d4.w;
        sv[0] = s4.x; sv[1] = s4.y; sv[2] = s4.z; sv[3] = s4.w;
      } else {
#pragma unroll
        for (int k = 0; k < 4; ++k) {
          dv[k] = (ib + k < i1) ? edst[ib + k] : -1;
          sv[k] = (ib + k < i1) ? esrc[ib + k] : 0;
        }
      }
#pragma unroll
      for (int k = 0; k < 4; ++k) {
        const int d = dv[k];
        if (d >= c0 && d < c1) {
          const uint pk = pdsl[d >> 2];
          const uint pfx = (pk >> ((uint)(d & 3) * 8u)) & 0xffu;
          csr[rofs[d] + (int)pfx + (int)rank8[ib + k]] = sv[k];
        }
      }
    }
    return;
  }
  // ---- gemm32 part
  const int lane = threadIdx.x & 63;
  const int wv = threadIdx.x >> 6;
  const int m0 = (blockIdx.x * 4 + wv) * 32;
  if (m0 >= M) return;
  const int lr = lane & 15;
  const int kg = (lane >> 4) * 8;

  half8 hf[2][4];
  const half8 hz = {};
#pragma unroll
  for (int mt = 0; mt < 2; ++mt) {
    const int row = m0 + mt * 16 + lr;
    if (row < M) {
      const float s = ns[row];
#pragma unroll
      for (int kt = 0; kt < 4; ++kt) {
        const float4 a = *reinterpret_cast<const float4*>(X + (size_t)row * D + kt * 32 + kg);
        const float4 b = *reinterpret_cast<const float4*>(X + (size_t)row * D + kt * 32 + kg + 4);
        half8 hv;
        hv[0] = (_Float16)(a.x * s); hv[1] = (_Float16)(a.y * s);
        hv[2] = (_Float16)(a.z * s); hv[3] = (_Float16)(a.w * s);
        hv[4] = (_Float16)(b.x * s); hv[5] = (_Float16)(b.y * s);
        hv[6] = (_Float16)(b.z * s); hv[7] = (_Float16)(b.w * s);
        hf[mt][kt] = hv;
      }
    } else {
#pragma unroll
      for (int kt = 0; kt < 4; ++kt) hf[mt][kt] = hz;
    }
  }

  f32x4 acc[8][2];
#pragma unroll
  for (int nt = 0; nt < 8; ++nt) { acc[nt][0] = (f32x4)(0.f); acc[nt][1] = (f32x4)(0.f); }

#pragma unroll
  for (int nt = 0; nt < 8; ++nt) {
    const ushort* wb = Wt + (size_t)(nt * 16 + lr) * D + kg;
#pragma unroll
    for (int kt = 0; kt < 4; ++kt) {
      half8 wf = *reinterpret_cast<const half8*>(wb + kt * 32);
      acc[nt][0] = __builtin_amdgcn_mfma_f32_16x16x32_f16(wf, hf[0][kt], acc[nt][0], 0, 0, 0);
      acc[nt][1] = __builtin_amdgcn_mfma_f32_16x16x32_f16(wf, hf[1][kt], acc[nt][1], 0, 0, 0);
    }
  }

  const int mo = lane & 15;
  const int no = (lane >> 4) * 4;
#pragma unroll
  for (int mt = 0; mt < 2; ++mt) {
    const int row = m0 + mt * 16 + mo;
    if (row < M) {
#pragma unroll
      for (int nt = 0; nt < 8; ++nt) {
        uint2 u;
        u.x = pack_f16x2(acc[nt][mt][0], acc[nt][mt][1]);
        u.y = pack_f16x2(acc[nt][mt][2], acc[nt][mt][3]);
        *reinterpret_cast<uint2*>(out + (size_t)row * D + nt * 16 + no) = u;
      }
    }
  }
}

// ---- k_spgm: FUSED spmm + next-layer GEMM. Block owns 128 dst rows. ----

__global__ __launch_bounds__(256) void k_spgm(const uint* __restrict__ hs,
                                              const int* __restrict__ csr,
                                              const int* __restrict__ rofs,
                                              const float* __restrict__ nd,
                                              const float* __restrict__ ns,
                                              const float* __restrict__ CA,
                                              const float* __restrict__ CB,
                                              const ushort* __restrict__ Wt,
                                              ushort* __restrict__ out, int N) {
  __shared__ ushort A[128 * 136];   // 34816 B; row stride 272 B (16B-aligned)
  const int t = threadIdx.x;
  const int lane = t & 63;
  const int c16 = lane & 15;
  const int gb = lane & ~15;
  const int g = t >> 4;            // group 0..15
  const int rbase = blockIdx.x * 128;

  // ---- Phase A: spmm into LDS ----
#pragma unroll 1
  for (int r = 0; r < 8; ++r) {
    const int rl = g + 16 * r;     // row_local 0..127
    const int d = rbase + rl;
    uint4 uo = make_uint4(0u, 0u, 0u, 0u);
    if (d < N) {
      const int beg = rofs[d], end = rofs[d + 1];
      float acc[8];
#pragma unroll
      for (int j = 0; j < 8; ++j) acc[j] = 0.f;
      for (int eb = beg; eb < end; eb += 16) {
        const int len = min(16, end - eb);
        const int idx = csr[min(eb + c16, end - 1)];
#pragma unroll 1
        for (int j = 0; j < len; j += 4) {
          const int l1 = min(j + 1, len - 1), l2 = min(j + 2, len - 1), l3 = min(j + 3, len - 1);
          const int s0 = __shfl(idx, gb + j);
          const int s1 = __shfl(idx, gb + l1);
          const int s2 = __shfl(idx, gb + l2);
          const int s3 = __shfl(idx, gb + l3);
          const float w1 = (j + 1 < len) ? 1.f : 0.f;
          const float w2 = (j + 2 < len) ? 1.f : 0.f;
          const float w3 = (j + 3 < len) ? 1.f : 0.f;
          const uint4 v0 = *reinterpret_cast<const uint4*>(hs + (size_t)s0 * 64 + c16 * 4);
          const uint4 v1 = *reinterpret_cast<const uint4*>(hs + (size_t)s1 * 64 + c16 * 4);
          const uint4 v2 = *reinterpret_cast<const uint4*>(hs + (size_t)s2 * 64 + c16 * 4);
          const uint4 v3 = *reinterpret_cast<const uint4*>(hs + (size_t)s3 * 64 + c16 * 4);
#pragma unroll
          for (int q = 0; q < 4; ++q) {
            const float2 a0 = unpack_f16x2((&v0.x)[q]);
            const float2 a1 = unpack_f16x2((&v1.x)[q]);
            const float2 a2 = unpack_f16x2((&v2.x)[q]);
            const float2 a3 = unpack_f16x2((&v3.x)[q]);
            acc[q * 2]     += a0.x;
            acc[q * 2 + 1] += a0.y;
            acc[q * 2]     = fmaf(a1.x, w1, acc[q * 2]);
            acc[q * 2 + 1] = fmaf(a1.y, w1, acc[q * 2 + 1]);
            acc[q * 2]     = fmaf(a2.x, w2, acc[q * 2]);
            acc[q * 2 + 1] = fmaf(a2.y, w2, acc[q * 2 + 1]);
            acc[q * 2]     = fmaf(a3.x, w3, acc[q * 2]);
            acc[q * 2 + 1] = fmaf(a3.y, w3, acc[q * 2 + 1]);
          }
        }
      }
      const float ndv = nd[d];
      const float s = ns[d];
      const float4 ca0 = *reinterpret_cast<const float4*>(CA + c16 * 8);
      const float4 ca1 = *reinterpret_cast<const float4*>(CA + c16 * 8 + 4);
      const float4 cb0 = *reinterpret_cast<const float4*>(CB + c16 * 8);
      const float4 cb1 = *reinterpret_cast<const float4*>(CB + c16 * 8 + 4);
      float rv[8];
      rv[0] = acc[0] * ndv * ca0.x + cb0.x;
      rv[1] = acc[1] * ndv * ca0.y + cb0.y;
      rv[2] = acc[2] * ndv * ca0.z + cb0.z;
      rv[3] = acc[3] * ndv * ca0.w + cb0.w;
      rv[4] = acc[4] * ndv * ca1.x + cb1.x;
      rv[5] = acc[5] * ndv * ca1.y + cb1.y;
      rv[6] = acc[6] * ndv * ca1.z + cb1.z;
      rv[7] = acc[7] * ndv * ca1.w + cb1.w;
#pragma unroll
      for (int j = 0; j < 8; ++j) rv[j] = fmaxf(rv[j], 0.f) * s;
      uo.x = pack_f16x2(rv[0], rv[1]);
      uo.y = pack_f16x2(rv[2], rv[3]);
      uo.z = pack_f16x2(rv[4], rv[5]);
      uo.w = pack_f16x2(rv[6], rv[7]);
    }
    *reinterpret_cast<uint4*>(&A[rl * 136 + c16 * 8]) = uo;
  }
  __syncthreads();

  // ---- Phase B: GEMM from LDS ----
  const int w = t >> 6;
  const int m0l = w * 32;
  const int m0 = rbase + m0l;
  if (m0 >= N) return;
  const int lr = lane & 15;
  const int kg = (lane >> 4) * 8;
  half8 hf[2][4];
#pragma unroll
  for (int mt = 0; mt < 2; ++mt) {
    const int row_l = m0l + mt * 16 + lr;
#pragma unroll
    for (int kt = 0; kt < 4; ++kt)
      hf[mt][kt] = *reinterpret_cast<const half8*>(&A[row_l * 136 + kt * 32 + kg]);
  }
  const int no = (lane >> 4) * 4;
#pragma unroll
  for (int nt = 0; nt < 8; ++nt) {
    f32x4 a0 = (f32x4)(0.f), a1 = (f32x4)(0.f);
    const ushort* wb = Wt + (size_t)(nt * 16 + lr) * D + kg;
#pragma unroll
    for (int kt = 0; kt < 4; ++kt) {
      half8 wf = *reinterpret_cast<const half8*>(wb + kt * 32);
      a0 = __builtin_amdgcn_mfma_f32_16x16x32_f16(wf, hf[0][kt], a0, 0, 0, 0);
      a1 = __builtin_amdgcn_mfma_f32_16x16x32_f16(wf, hf[1][kt], a1, 0, 0, 0);
    }
    const int r0 = m0 + lr, r1 = m0 + 16 + lr;
    if (r0 < N) {
      uint2 u; u.x = pack_f16x2(a0[0], a0[1]); u.y = pack_f16x2(a0[2], a0[3]);
      *reinterpret_cast<uint2*>(out + (size_t)r0 * D + nt * 16 + no) = u;
    }
    if (r1 < N) {
      uint2 u; u.x = pack_f16x2(a1[0], a1[1]); u.y = pack_f16x2(a1[2], a1[3]);
      *reinterpret_cast<uint2*>(out + (size_t)r1 * D + nt * 16 + no) = u;
    }
  }
}

// ---------------- SpMM (standalone, final layer -> fp32 out) ----------------

__global__ __launch_bounds__(256) void k_spmm16(const uint* __restrict__ hs,
                                                const int* __restrict__ csr,
                                                const int* __restrict__ rofs,
                                                const float* __restrict__ nd,
                                                const float* __restrict__ CA,
                                                const float* __restrict__ CB,
                                                float* __restrict__ outf, int N) {
  const int t = threadIdx.x;
  const int lane = t & 63;
  const int c16 = lane & 15;
  const int gb = lane & ~15;
  const int d = blockIdx.x * 16 + (t >> 4);
  if (d >= N) return;
  const int beg = rofs[d], end = rofs[d + 1];

  float acc[8];
#pragma unroll
  for (int j = 0; j < 8; ++j) acc[j] = 0.f;

  for (int base = beg; base < end; base += 16) {
    const int len = min(16, end - base);
    const int idx = csr[min(base + c16, end - 1)];
#pragma unroll 1
    for (int j = 0; j < len; j += 4) {
      const int l1 = min(j + 1, len - 1), l2 = min(j + 2, len - 1), l3 = min(j + 3, len - 1);
      const int s0 = __shfl(idx, gb + j);
      const int s1 = __shfl(idx, gb + l1);
      const int s2 = __shfl(idx, gb + l2);
      const int s3 = __shfl(idx, gb + l3);
      const float w1 = (j + 1 < len) ? 1.f : 0.f;
      const float w2 = (j + 2 < len) ? 1.f : 0.f;
      const float w3 = (j + 3 < len) ? 1.f : 0.f;
      const uint4 v0 = *reinterpret_cast<const uint4*>(hs + (size_t)s0 * 64 + c16 * 4);
      const uint4 v1 = *reinterpret_cast<const uint4*>(hs + (size_t)s1 * 64 + c16 * 4);
      const uint4 v2 = *reinterpret_cast<const uint4*>(hs + (size_t)s2 * 64 + c16 * 4);
      const uint4 v3 = *reinterpret_cast<const uint4*>(hs + (size_t)s3 * 64 + c16 * 4);
#pragma unroll
      for (int q = 0; q < 4; ++q) {
        const float2 a0 = unpack_f16x2((&v0.x)[q]);
        const float2 a1 = unpack_f16x2((&v1.x)[q]);
        const float2 a2 = unpack_f16x2((&v2.x)[q]);
        const float2 a3 = unpack_f16x2((&v3.x)[q]);
        acc[q * 2]     += a0.x;
        acc[q * 2 + 1] += a0.y;
        acc[q * 2]     = fmaf(a1.x, w1, acc[q * 2]);
        acc[q * 2 + 1] = fmaf(a1.y, w1, acc[q * 2 + 1]);
        acc[q * 2]     = fmaf(a2.x, w2, acc[q * 2]);
        acc[q * 2 + 1] = fmaf(a2.y, w2, acc[q * 2 + 1]);
        acc[q * 2]     = fmaf(a3.x, w3, acc[q * 2]);
        acc[q * 2 + 1] = fmaf(a3.y, w3, acc[q * 2 + 1]);
      }
    }
  }

  const float ndv = nd[d];
  const float4 ca0 = *reinterpret_cast<const float4*>(CA + c16 * 8);
  const float4 ca1 = *reinterpret_cast<const float4*>(CA + c16 * 8 + 4);
  const float4 cb0 = *reinterpret_cast<const float4*>(CB + c16 * 8);
  const float4 cb1 = *reinterpret_cast<const float4*>(CB + c16 * 8 + 4);
  float4 o0, o1;
  o0.x = acc[0] * ndv * ca0.x + cb0.x;
  o0.y = acc[1] * ndv * ca0.y + cb0.y;
  o0.z = acc[2] * ndv * ca0.z + cb0.z;
  o0.w = acc[3] * ndv * ca0.w + cb0.w;
  o1.x = acc[4] * ndv * ca1.x + cb1.x;
  o1.y = acc[5] * ndv * ca1.y + cb1.y;
  o1.z = acc[6] * ndv * ca1.z + cb1.z;
  o1.w = acc[7] * ndv * ca1.w + cb1.w;
  *reinterpret_cast<float4*>(outf + (size_t)d * D + c16 * 8) = o0;
  *reinterpret_cast<float4*>(outf + (size_t)d * D + c16 * 8 + 4) = o1;
}

// ---------------- launch ----------------

extern "C" void kernel_launch(void* const* d_in, const int* in_sizes, int n_in,
                              void* d_out, int out_size, void* d_ws, size_t ws_size,
                              hipStream_t stream) {
  const float* x = (const float*)d_in[0];
  const int* esrc = (const int*)d_in[1];
  const int* edst = (const int*)d_in[2];
  const float* W0 = (const float*)d_in[3];
  const float* b0 = (const float*)d_in[4];
  const float* W1 = (const float*)d_in[5];
  const float* b1 = (const float*)d_in[6];
  const float* W2 = (const float*)d_in[7];
  const float* b2 = (const float*)d_in[8];
  const float* g0 = (const float*)d_in[9];
  const float* be0 = (const float*)d_in[10];
  const float* m0 = (const float*)d_in[11];
  const float* v0 = (const float*)d_in[12];
  const float* g1 = (const float*)d_in[13];
  const float* be1 = (const float*)d_in[14];
  const float* m1 = (const float*)d_in[15];
  const float* v1 = (const float*)d_in[16];
  const int N = in_sizes[0] / D;
  const int E = in_sizes[1];

  const int SB = (((E + NSL - 1) / NSL) + 3) & ~3;   // 4-aligned slice size
  const int BPC = (N + 7) / 8;

  char* p = (char*)d_ws;
  auto carve = [&](size_t bytes) {
    char* r = p;
    p += (bytes + 255) & ~(size_t)255;
    return (void*)r;
  };
  uint* hs16 = (uint*)carve((size_t)N * 64 * 4);           // f16 ping buffer in ws
  ushort* Wt = (ushort*)carve((size_t)3 * D * D * 2);
  float* CA = (float*)carve((size_t)3 * D * 4);
  float* CB = (float*)carve((size_t)3 * D * 4);
  float* ns = (float*)carve((size_t)N * 4);
  float* nd = (float*)carve((size_t)N * 4);
  uint* pd = (uint*)carve((size_t)NSL * PBU * 4);
  uint* ps = (uint*)carve((size_t)NSL * PBU * 4);
  uchar* rank8 = (uchar*)carve((size_t)E);
  int* totd = (int*)carve((size_t)N * 4);
  int* rofs = (int*)carve((size_t)(N + 1) * 4);
  const int nch = (N + 1023) / 1024;
  int* csum = (int*)carve((size_t)nch * 4);
  int* ticket = (int*)carve(256);
  int* csr = (int*)carve((size_t)E * 4);
  uint* hsOut = (uint*)d_out;  // f16 pong buffer in d_out (fully rewritten at the end)

  hipMemsetAsync(ticket, 0, 4, stream);
  k_build1<<<113, 1024, 0, stream>>>(esrc, edst, W0, W1, W2, b0, b1, b2,
                                     g0, be0, m0, v0, g1, be1, m1, v1,
                                     pd, ps, rank8, Wt, CA, CB, E, SB);
  k_build2s<<<nch, 256, 0, stream>>>(pd, ps, totd, ns, nd, csum, rofs, ticket, N, nch);
  k_scan_final<<<nch, 256, 0, stream>>>(totd, csum, rofs, N);

  const int gb = (N + 127) / 128;
  const int fb = (N + 127) / 128;
  const int sb = (N + 15) / 16;
  // layer-0 GEMM (f32 input) + blocked scatter merged
  k_sg<<<gb + 256, 256, 0, stream>>>(x, Wt, ns, (ushort*)hs16, esrc, edst, rank8, pd, rofs,
                                     csr, N, E, SB, BPC, gb);
  // fused: spmm L0 + gemm L1  -> d_out (f16 region)
  k_spgm<<<fb, 256, 0, stream>>>(hs16, csr, rofs, nd, ns, CA, CB, Wt + 16384,
                                 (ushort*)hsOut, N);
  // fused: spmm L1 + gemm L2  -> hs16
  k_spgm<<<fb, 256, 0, stream>>>(hsOut, csr, rofs, nd, ns, CA + D, CB + D, Wt + 32768,
                                 (ushort*)hs16, N);
  // final spmm L2 -> fp32 out
  k_spmm16<<<sb, 256, 0, stream>>>(hs16, csr, rofs, nd, CA + 2 * D, CB + 2 * D,
                                   (float*)d_out, N);
}

// Round 17
// 230.064 us; speedup vs baseline: 1.5208x; 1.1305x over previous
//
#include <hip/hip_runtime.h>
#include <hip/hip_fp16.h>
#include <math.h>

#define D 128
#define NSL 32          // edge slices
#define PBU 25088       // packed u8 counters (uints) -> supports N <= 100352

typedef _Float16 half8 __attribute__((ext_vector_type(8)));
typedef float f32x4 __attribute__((ext_vector_type(4)));

__device__ inline uint pack_f16x2(float a, float b) {
  __half2 h = __floats2half2_rn(a, b);
  return *reinterpret_cast<uint*>(&h);
}
__device__ inline float2 unpack_f16x2(uint p) {
  __half2 h = *reinterpret_cast<__half2*>(&p);
  return __half22float2(h);
}
__device__ inline uint mdiv40(uint x, uint M) {  // x / d with M = ceil(2^40/d)
  return (uint)(((unsigned long long)x * M) >> 40);
}

// ---------------- build1: fused {dst-hist+rank, src-hist, Wt transpose, CA/CB} ----------

__global__ __launch_bounds__(1024) void k_build1(const int* __restrict__ esrc,
                                                 const int* __restrict__ edst,
                                                 const float* __restrict__ W0,
                                                 const float* __restrict__ W1,
                                                 const float* __restrict__ W2,
                                                 const float* __restrict__ b0,
                                                 const float* __restrict__ b1,
                                                 const float* __restrict__ b2,
                                                 const float* __restrict__ g0,
                                                 const float* __restrict__ be0,
                                                 const float* __restrict__ mu0,
                                                 const float* __restrict__ vr0,
                                                 const float* __restrict__ g1,
                                                 const float* __restrict__ be1,
                                                 const float* __restrict__ mu1,
                                                 const float* __restrict__ vr1,
                                                 uint* __restrict__ pd,
                                                 uint* __restrict__ ps,
                                                 uchar* __restrict__ rank8,
                                                 ushort* __restrict__ Wt,
                                                 float* __restrict__ CA,
                                                 float* __restrict__ CB,
                                                 int E, int SB) {
  __shared__ uint h[PBU];   // ~98 KB static LDS (hist blocks only)
  const int b = blockIdx.x;
  const int t = threadIdx.x;
  if (b < 32) {             // ---- dst histogram + rank record
    for (int j = t; j < PBU; j += 1024) h[j] = 0u;
    __syncthreads();
    const int i0 = b * SB, i1 = min(i0 + SB, E);
    for (int i = i0 + t; i < i1; i += 1024) {
      const int d = edst[i];
      const uint sh = (uint)(d & 3) * 8u;
      const uint old = atomicAdd(&h[d >> 2], 1u << sh);
      rank8[i] = (uchar)((old >> sh) & 0xffu);
    }
    __syncthreads();
    uint* p = pd + (size_t)b * PBU;
    for (int j = t; j < PBU; j += 1024) p[j] = h[j];
  } else if (b < 64) {      // ---- src histogram (counts only)
    const int sl = b - 32;
    for (int j = t; j < PBU; j += 1024) h[j] = 0u;
    __syncthreads();
    const int i0 = sl * SB, i1 = min(i0 + SB, E);
    for (int i = i0 + t; i < i1; i += 1024) {
      const int s = esrc[i];
      atomicAdd(&h[s >> 2], 1u << ((uint)(s & 3) * 8u));
    }
    __syncthreads();
    uint* p = ps + (size_t)sl * PBU;
    for (int j = t; j < PBU; j += 1024) p[j] = h[j];
  } else if (b < 112) {     // ---- Wt[l][n][k] = f16(W_l[k][n])
    const int li = (b - 64) * 1024 + t;   // 0..49151
    const int l = li >> 14;
    const int i = li & 16383;
    const int n = i >> 7, k = i & 127;
    const float* W = (l == 0) ? W0 : ((l == 1) ? W1 : W2);
    Wt[li] = __half_as_ushort(__float2half_rn(W[k * D + n]));
  } else if (t < D) {       // ---- CA/CB fold bias+BN
    const int c = t;
    float A0 = g0[c] * rsqrtf(vr0[c] + 1e-5f);
    CA[c] = A0;
    CB[c] = (b0[c] - mu0[c]) * A0 + be0[c];
    float A1 = g1[c] * rsqrtf(vr1[c] + 1e-5f);
    CA[D + c] = A1;
    CB[D + c] = (b1[c] - mu1[c]) * A1 + be1[c];
    CA[2 * D + c] = 1.f;
    CB[2 * D + c] = b2[c];
  }
}

// ---- build2s: reduceN + chunk sum; LAST block serial-scans chunk sums ----

__global__ __launch_bounds__(256) void k_build2s(uint* __restrict__ pd,
                                                 const uint* __restrict__ ps,
                                                 int* __restrict__ totd,
                                                 float* __restrict__ ns,
                                                 float* __restrict__ nd,
                                                 int* __restrict__ csum,
                                                 int* __restrict__ rofs,
                                                 int* __restrict__ ticket,
                                                 int N, int nch) {
  __shared__ int sd[256];
  __shared__ int lastf;
  const int t = threadIdx.x;
  const int j = blockIdx.x * 256 + t;    // packed uint index (4 nodes), j < PBU
  const int n0 = j * 4;
  uint r0 = 0, r1 = 0, r2 = 0, r3 = 0;
  uint s0 = 0, s1 = 0, s2 = 0, s3 = 0;
#pragma unroll
  for (int sl = 0; sl < NSL; ++sl) {
    const uint v = pd[(size_t)sl * PBU + j];
    pd[(size_t)sl * PBU + j] = r0 | (r1 << 8) | (r2 << 16) | (r3 << 24);
    r0 += v & 0xffu; r1 += (v >> 8) & 0xffu; r2 += (v >> 16) & 0xffu; r3 += (v >> 24) & 0xffu;
    const uint w = ps[(size_t)sl * PBU + j];
    s0 += w & 0xffu; s1 += (w >> 8) & 0xffu; s2 += (w >> 16) & 0xffu; s3 += (w >> 24) & 0xffu;
  }
  const uint rr[4] = {r0, r1, r2, r3};
  const uint ss[4] = {s0, s1, s2, s3};
  int tot = 0;
#pragma unroll
  for (int k = 0; k < 4; ++k) {
    if (n0 + k < N) {
      totd[n0 + k] = (int)rr[k];
      nd[n0 + k] = rsqrtf((float)max(rr[k], 1u));
      ns[n0 + k] = rsqrtf((float)max(ss[k], 1u));
      tot += (int)rr[k];
    }
  }
  sd[t] = tot; __syncthreads();
  for (int off = 128; off > 0; off >>= 1) {
    if (t < off) sd[t] += sd[t + off];
    __syncthreads();
  }
  if (t == 0) {
    csum[blockIdx.x] = sd[0];
    __threadfence();
    lastf = (atomicAdd(ticket, 1) == nch - 1) ? 1 : 0;
  }
  __syncthreads();
  if (lastf && t < 64) {
    __threadfence();
    int run = 0;
    for (int b0 = 0; b0 < nch; b0 += 64) {
      const int idx = b0 + t;
      int v = (idx < nch) ? __hip_atomic_load(&csum[idx], __ATOMIC_RELAXED,
                                              __HIP_MEMORY_SCOPE_AGENT) : 0;
      int sc = v;
#pragma unroll
      for (int off = 1; off < 64; off <<= 1) {
        int u = __shfl_up(sc, off);
        if (t >= off) sc += u;
      }
      if (idx < nch) csum[idx] = run + sc - v;
      run += __shfl(sc, 63);
    }
    if (t == 0) rofs[N] = run;
  }
}

// ---------------- final per-node rofs scan ----------------

__global__ __launch_bounds__(256) void k_scan_final(const int* __restrict__ totd,
                                                    const int* __restrict__ csum,
                                                    int* __restrict__ rofs, int n) {
  __shared__ int sd[256];
  const int b = blockIdx.x, t = threadIdx.x;
  const int base = b * 1024 + t * 4;
  int v[4]; int s = 0;
#pragma unroll
  for (int i = 0; i < 4; ++i) { v[i] = (base + i < n) ? totd[base + i] : 0; s += v[i]; }
  sd[t] = s; __syncthreads();
  for (int off = 1; off < 256; off <<= 1) {
    int x = (t >= off) ? sd[t - off] : 0;
    __syncthreads();
    sd[t] += x;
    __syncthreads();
  }
  int o = sd[t] - s + csum[b];
#pragma unroll
  for (int i = 0; i < 4; ++i) {
    if (base + i < n) { rofs[base + i] = o; o += v[i]; }
  }
}

// ---- sg: merged {layer-0 GEMM (f32 input, ns folded)} + {scatter, 4 edges/thread} ----

__global__ __launch_bounds__(256) void k_sg(const float* __restrict__ X,
                                            const ushort* __restrict__ Wt,
                                            const float* __restrict__ ns,
                                            ushort* __restrict__ out,
                                            const int* __restrict__ esrc,
                                            const int* __restrict__ edst,
                                            const uchar* __restrict__ rank8,
                                            const uint* __restrict__ pd,
                                            const int* __restrict__ rofs,
                                            int* __restrict__ csr,
                                            int M, int E, uint Msb, int GB) {
  if ((int)blockIdx.x >= GB) {   // ---- scatter: 4 independent edge chains per thread
    const int base = ((int)blockIdx.x - GB) * 1024 + threadIdx.x;
#pragma unroll
    for (int k = 0; k < 4; ++k) {
      const int i = base + k * 256;
      if (i < E) {
        const int d = edst[i];
        const uint sl = mdiv40((uint)i, Msb);
        const uint pk = pd[(size_t)sl * PBU + (d >> 2)];
        const uint pfx = (pk >> ((uint)(d & 3) * 8u)) & 0xffu;
        csr[rofs[d] + (int)pfx + (int)rank8[i]] = esrc[i];
      }
    }
    return;
  }
  // ---- gemm32 part
  const int lane = threadIdx.x & 63;
  const int wv = threadIdx.x >> 6;
  const int m0 = (blockIdx.x * 4 + wv) * 32;
  if (m0 >= M) return;
  const int lr = lane & 15;
  const int kg = (lane >> 4) * 8;

  half8 hf[2][4];
  const half8 hz = {};
#pragma unroll
  for (int mt = 0; mt < 2; ++mt) {
    const int row = m0 + mt * 16 + lr;
    if (row < M) {
      const float s = ns[row];
#pragma unroll
      for (int kt = 0; kt < 4; ++kt) {
        const float4 a = *reinterpret_cast<const float4*>(X + (size_t)row * D + kt * 32 + kg);
        const float4 b = *reinterpret_cast<const float4*>(X + (size_t)row * D + kt * 32 + kg + 4);
        half8 hv;
        hv[0] = (_Float16)(a.x * s); hv[1] = (_Float16)(a.y * s);
        hv[2] = (_Float16)(a.z * s); hv[3] = (_Float16)(a.w * s);
        hv[4] = (_Float16)(b.x * s); hv[5] = (_Float16)(b.y * s);
        hv[6] = (_Float16)(b.z * s); hv[7] = (_Float16)(b.w * s);
        hf[mt][kt] = hv;
      }
    } else {
#pragma unroll
      for (int kt = 0; kt < 4; ++kt) hf[mt][kt] = hz;
    }
  }

  f32x4 acc[8][2];
#pragma unroll
  for (int nt = 0; nt < 8; ++nt) { acc[nt][0] = (f32x4)(0.f); acc[nt][1] = (f32x4)(0.f); }

#pragma unroll
  for (int nt = 0; nt < 8; ++nt) {
    const ushort* wb = Wt + (size_t)(nt * 16 + lr) * D + kg;
#pragma unroll
    for (int kt = 0; kt < 4; ++kt) {
      half8 wf = *reinterpret_cast<const half8*>(wb + kt * 32);
      acc[nt][0] = __builtin_amdgcn_mfma_f32_16x16x32_f16(wf, hf[0][kt], acc[nt][0], 0, 0, 0);
      acc[nt][1] = __builtin_amdgcn_mfma_f32_16x16x32_f16(wf, hf[1][kt], acc[nt][1], 0, 0, 0);
    }
  }

  const int mo = lane & 15;
  const int no = (lane >> 4) * 4;
#pragma unroll
  for (int mt = 0; mt < 2; ++mt) {
    const int row = m0 + mt * 16 + mo;
    if (row < M) {
#pragma unroll
      for (int nt = 0; nt < 8; ++nt) {
        uint2 u;
        u.x = pack_f16x2(acc[nt][mt][0], acc[nt][mt][1]);
        u.y = pack_f16x2(acc[nt][mt][2], acc[nt][mt][3]);
        *reinterpret_cast<uint2*>(out + (size_t)row * D + nt * 16 + no) = u;
      }
    }
  }
}

// ---- k_spgm: FUSED spmm + next-layer GEMM. Block owns 128 dst rows. ----

__global__ __launch_bounds__(256) void k_spgm(const uint* __restrict__ hs,
                                              const int* __restrict__ csr,
                                              const int* __restrict__ rofs,
                                              const float* __restrict__ nd,
                                              const float* __restrict__ ns,
                                              const float* __restrict__ CA,
                                              const float* __restrict__ CB,
                                              const ushort* __restrict__ Wt,
                                              ushort* __restrict__ out, int N) {
  __shared__ ushort A[128 * 136];   // 34816 B; row stride 272 B (16B-aligned)
  const int t = threadIdx.x;
  const int lane = t & 63;
  const int c16 = lane & 15;
  const int gb = lane & ~15;
  const int g = t >> 4;            // group 0..15
  const int rbase = blockIdx.x * 128;

  // ---- Phase A: spmm into LDS ----
#pragma unroll 1
  for (int r = 0; r < 8; ++r) {
    const int rl = g + 16 * r;     // row_local 0..127
    const int d = rbase + rl;
    uint4 uo = make_uint4(0u, 0u, 0u, 0u);
    if (d < N) {
      const int beg = rofs[d], end = rofs[d + 1];
      float acc[8];
#pragma unroll
      for (int j = 0; j < 8; ++j) acc[j] = 0.f;
      for (int eb = beg; eb < end; eb += 16) {
        const int len = min(16, end - eb);
        const int idx = csr[min(eb + c16, end - 1)];
#pragma unroll 1
        for (int j = 0; j < len; j += 4) {
          const int l1 = min(j + 1, len - 1), l2 = min(j + 2, len - 1), l3 = min(j + 3, len - 1);
          const int s0 = __shfl(idx, gb + j);
          const int s1 = __shfl(idx, gb + l1);
          const int s2 = __shfl(idx, gb + l2);
          const int s3 = __shfl(idx, gb + l3);
          const float w1 = (j + 1 < len) ? 1.f : 0.f;
          const float w2 = (j + 2 < len) ? 1.f : 0.f;
          const float w3 = (j + 3 < len) ? 1.f : 0.f;
          const uint4 v0 = *reinterpret_cast<const uint4*>(hs + (size_t)s0 * 64 + c16 * 4);
          const uint4 v1 = *reinterpret_cast<const uint4*>(hs + (size_t)s1 * 64 + c16 * 4);
          const uint4 v2 = *reinterpret_cast<const uint4*>(hs + (size_t)s2 * 64 + c16 * 4);
          const uint4 v3 = *reinterpret_cast<const uint4*>(hs + (size_t)s3 * 64 + c16 * 4);
#pragma unroll
          for (int q = 0; q < 4; ++q) {
            const float2 a0 = unpack_f16x2((&v0.x)[q]);
            const float2 a1 = unpack_f16x2((&v1.x)[q]);
            const float2 a2 = unpack_f16x2((&v2.x)[q]);
            const float2 a3 = unpack_f16x2((&v3.x)[q]);
            acc[q * 2]     += a0.x;
            acc[q * 2 + 1] += a0.y;
            acc[q * 2]     = fmaf(a1.x, w1, acc[q * 2]);
            acc[q * 2 + 1] = fmaf(a1.y, w1, acc[q * 2 + 1]);
            acc[q * 2]     = fmaf(a2.x, w2, acc[q * 2]);
            acc[q * 2 + 1] = fmaf(a2.y, w2, acc[q * 2 + 1]);
            acc[q * 2]     = fmaf(a3.x, w3, acc[q * 2]);
            acc[q * 2 + 1] = fmaf(a3.y, w3, acc[q * 2 + 1]);
          }
        }
      }
      const float ndv = nd[d];
      const float s = ns[d];
      const float4 ca0 = *reinterpret_cast<const float4*>(CA + c16 * 8);
      const float4 ca1 = *reinterpret_cast<const float4*>(CA + c16 * 8 + 4);
      const float4 cb0 = *reinterpret_cast<const float4*>(CB + c16 * 8);
      const float4 cb1 = *reinterpret_cast<const float4*>(CB + c16 * 8 + 4);
      float rv[8];
      rv[0] = acc[0] * ndv * ca0.x + cb0.x;
      rv[1] = acc[1] * ndv * ca0.y + cb0.y;
      rv[2] = acc[2] * ndv * ca0.z + cb0.z;
      rv[3] = acc[3] * ndv * ca0.w + cb0.w;
      rv[4] = acc[4] * ndv * ca1.x + cb1.x;
      rv[5] = acc[5] * ndv * ca1.y + cb1.y;
      rv[6] = acc[6] * ndv * ca1.z + cb1.z;
      rv[7] = acc[7] * ndv * ca1.w + cb1.w;
#pragma unroll
      for (int j = 0; j < 8; ++j) rv[j] = fmaxf(rv[j], 0.f) * s;
      uo.x = pack_f16x2(rv[0], rv[1]);
      uo.y = pack_f16x2(rv[2], rv[3]);
      uo.z = pack_f16x2(rv[4], rv[5]);
      uo.w = pack_f16x2(rv[6], rv[7]);
    }
    *reinterpret_cast<uint4*>(&A[rl * 136 + c16 * 8]) = uo;
  }
  __syncthreads();

  // ---- Phase B: GEMM from LDS ----
  const int w = t >> 6;
  const int m0l = w * 32;
  const int m0 = rbase + m0l;
  if (m0 >= N) return;
  const int lr = lane & 15;
  const int kg = (lane >> 4) * 8;
  half8 hf[2][4];
#pragma unroll
  for (int mt = 0; mt < 2; ++mt) {
    const int row_l = m0l + mt * 16 + lr;
#pragma unroll
    for (int kt = 0; kt < 4; ++kt)
      hf[mt][kt] = *reinterpret_cast<const half8*>(&A[row_l * 136 + kt * 32 + kg]);
  }
  const int no = (lane >> 4) * 4;
#pragma unroll
  for (int nt = 0; nt < 8; ++nt) {
    f32x4 a0 = (f32x4)(0.f), a1 = (f32x4)(0.f);
    const ushort* wb = Wt + (size_t)(nt * 16 + lr) * D + kg;
#pragma unroll
    for (int kt = 0; kt < 4; ++kt) {
      half8 wf = *reinterpret_cast<const half8*>(wb + kt * 32);
      a0 = __builtin_amdgcn_mfma_f32_16x16x32_f16(wf, hf[0][kt], a0, 0, 0, 0);
      a1 = __builtin_amdgcn_mfma_f32_16x16x32_f16(wf, hf[1][kt], a1, 0, 0, 0);
    }
    const int r0 = m0 + lr, r1 = m0 + 16 + lr;
    if (r0 < N) {
      uint2 u; u.x = pack_f16x2(a0[0], a0[1]); u.y = pack_f16x2(a0[2], a0[3]);
      *reinterpret_cast<uint2*>(out + (size_t)r0 * D + nt * 16 + no) = u;
    }
    if (r1 < N) {
      uint2 u; u.x = pack_f16x2(a1[0], a1[1]); u.y = pack_f16x2(a1[2], a1[3]);
      *reinterpret_cast<uint2*>(out + (size_t)r1 * D + nt * 16 + no) = u;
    }
  }
}

// ---------------- SpMM (standalone, final layer -> fp32 out) ----------------

__global__ __launch_bounds__(256) void k_spmm16(const uint* __restrict__ hs,
                                                const int* __restrict__ csr,
                                                const int* __restrict__ rofs,
                                                const float* __restrict__ nd,
                                                const float* __restrict__ CA,
                                                const float* __restrict__ CB,
                                                float* __restrict__ outf, int N) {
  const int t = threadIdx.x;
  const int lane = t & 63;
  const int c16 = lane & 15;
  const int gb = lane & ~15;
  const int d = blockIdx.x * 16 + (t >> 4);
  if (d >= N) return;
  const int beg = rofs[d], end = rofs[d + 1];

  float acc[8];
#pragma unroll
  for (int j = 0; j < 8; ++j) acc[j] = 0.f;

  for (int base = beg; base < end; base += 16) {
    const int len = min(16, end - base);
    const int idx = csr[min(base + c16, end - 1)];
#pragma unroll 1
    for (int j = 0; j < len; j += 4) {
      const int l1 = min(j + 1, len - 1), l2 = min(j + 2, len - 1), l3 = min(j + 3, len - 1);
      const int s0 = __shfl(idx, gb + j);
      const int s1 = __shfl(idx, gb + l1);
      const int s2 = __shfl(idx, gb + l2);
      const int s3 = __shfl(idx, gb + l3);
      const float w1 = (j + 1 < len) ? 1.f : 0.f;
      const float w2 = (j + 2 < len) ? 1.f : 0.f;
      const float w3 = (j + 3 < len) ? 1.f : 0.f;
      const uint4 v0 = *reinterpret_cast<const uint4*>(hs + (size_t)s0 * 64 + c16 * 4);
      const uint4 v1 = *reinterpret_cast<const uint4*>(hs + (size_t)s1 * 64 + c16 * 4);
      const uint4 v2 = *reinterpret_cast<const uint4*>(hs + (size_t)s2 * 64 + c16 * 4);
      const uint4 v3 = *reinterpret_cast<const uint4*>(hs + (size_t)s3 * 64 + c16 * 4);
#pragma unroll
      for (int q = 0; q < 4; ++q) {
        const float2 a0 = unpack_f16x2((&v0.x)[q]);
        const float2 a1 = unpack_f16x2((&v1.x)[q]);
        const float2 a2 = unpack_f16x2((&v2.x)[q]);
        const float2 a3 = unpack_f16x2((&v3.x)[q]);
        acc[q * 2]     += a0.x;
        acc[q * 2 + 1] += a0.y;
        acc[q * 2]     = fmaf(a1.x, w1, acc[q * 2]);
        acc[q * 2 + 1] = fmaf(a1.y, w1, acc[q * 2 + 1]);
        acc[q * 2]     = fmaf(a2.x, w2, acc[q * 2]);
        acc[q * 2 + 1] = fmaf(a2.y, w2, acc[q * 2 + 1]);
        acc[q * 2]     = fmaf(a3.x, w3, acc[q * 2]);
        acc[q * 2 + 1] = fmaf(a3.y, w3, acc[q * 2 + 1]);
      }
    }
  }

  const float ndv = nd[d];
  const float4 ca0 = *reinterpret_cast<const float4*>(CA + c16 * 8);
  const float4 ca1 = *reinterpret_cast<const float4*>(CA + c16 * 8 + 4);
  const float4 cb0 = *reinterpret_cast<const float4*>(CB + c16 * 8);
  const float4 cb1 = *reinterpret_cast<const float4*>(CB + c16 * 8 + 4);
  float4 o0, o1;
  o0.x = acc[0] * ndv * ca0.x + cb0.x;
  o0.y = acc[1] * ndv * ca0.y + cb0.y;
  o0.z = acc[2] * ndv * ca0.z + cb0.z;
  o0.w = acc[3] * ndv * ca0.w + cb0.w;
  o1.x = acc[4] * ndv * ca1.x + cb1.x;
  o1.y = acc[5] * ndv * ca1.y + cb1.y;
  o1.z = acc[6] * ndv * ca1.z + cb1.z;
  o1.w = acc[7] * ndv * ca1.w + cb1.w;
  *reinterpret_cast<float4*>(outf + (size_t)d * D + c16 * 8) = o0;
  *reinterpret_cast<float4*>(outf + (size_t)d * D + c16 * 8 + 4) = o1;
}

// ---------------- launch ----------------

extern "C" void kernel_launch(void* const* d_in, const int* in_sizes, int n_in,
                              void* d_out, int out_size, void* d_ws, size_t ws_size,
                              hipStream_t stream) {
  const float* x = (const float*)d_in[0];
  const int* esrc = (const int*)d_in[1];
  const int* edst = (const int*)d_in[2];
  const float* W0 = (const float*)d_in[3];
  const float* b0 = (const float*)d_in[4];
  const float* W1 = (const float*)d_in[5];
  const float* b1 = (const float*)d_in[6];
  const float* W2 = (const float*)d_in[7];
  const float* b2 = (const float*)d_in[8];
  const float* g0 = (const float*)d_in[9];
  const float* be0 = (const float*)d_in[10];
  const float* m0 = (const float*)d_in[11];
  const float* v0 = (const float*)d_in[12];
  const float* g1 = (const float*)d_in[13];
  const float* be1 = (const float*)d_in[14];
  const float* m1 = (const float*)d_in[15];
  const float* v1 = (const float*)d_in[16];
  const int N = in_sizes[0] / D;
  const int E = in_sizes[1];

  const int SB = (E + NSL - 1) / NSL;
  const uint Msb = (uint)(((1ULL << 40) + (unsigned long long)SB - 1) / (unsigned long long)SB);

  char* p = (char*)d_ws;
  auto carve = [&](size_t bytes) {
    char* r = p;
    p += (bytes + 255) & ~(size_t)255;
    return (void*)r;
  };
  uint* hs16 = (uint*)carve((size_t)N * 64 * 4);           // f16 ping buffer in ws
  ushort* Wt = (ushort*)carve((size_t)3 * D * D * 2);
  float* CA = (float*)carve((size_t)3 * D * 4);
  float* CB = (float*)carve((size_t)3 * D * 4);
  float* ns = (float*)carve((size_t)N * 4);
  float* nd = (float*)carve((size_t)N * 4);
  uint* pd = (uint*)carve((size_t)NSL * PBU * 4);
  uint* ps = (uint*)carve((size_t)NSL * PBU * 4);
  uchar* rank8 = (uchar*)carve((size_t)E);
  int* totd = (int*)carve((size_t)N * 4);
  int* rofs = (int*)carve((size_t)(N + 1) * 4);
  const int nch = (N + 1023) / 1024;
  int* csum = (int*)carve((size_t)nch * 4);
  int* ticket = (int*)carve(256);
  int* csr = (int*)carve((size_t)E * 4);
  uint* hsOut = (uint*)d_out;  // f16 pong buffer in d_out (fully rewritten at the end)

  hipMemsetAsync(ticket, 0, 4, stream);
  k_build1<<<113, 1024, 0, stream>>>(esrc, edst, W0, W1, W2, b0, b1, b2,
                                     g0, be0, m0, v0, g1, be1, m1, v1,
                                     pd, ps, rank8, Wt, CA, CB, E, SB);
  k_build2s<<<nch, 256, 0, stream>>>(pd, ps, totd, ns, nd, csum, rofs, ticket, N, nch);
  k_scan_final<<<nch, 256, 0, stream>>>(totd, csum, rofs, N);

  const int gb = (N + 127) / 128;
  const int scb = (E + 1023) / 1024;   // scatter blocks: 1024 edges each, 4/thread
  const int fb = (N + 127) / 128;
  const int sb = (N + 15) / 16;
  // layer-0 GEMM (f32 input) + scatter merged
  k_sg<<<gb + scb, 256, 0, stream>>>(x, Wt, ns, (ushort*)hs16, esrc, edst, rank8, pd, rofs,
                                     csr, N, E, Msb, gb);
  // fused: spmm L0 + gemm L1  -> d_out (f16 region)
  k_spgm<<<fb, 256, 0, stream>>>(hs16, csr, rofs, nd, ns, CA, CB, Wt + 16384,
                                 (ushort*)hsOut, N);
  // fused: spmm L1 + gemm L2  -> hs16
  k_spgm<<<fb, 256, 0, stream>>>(hsOut, csr, rofs, nd, ns, CA + D, CB + D, Wt + 32768,
                                 (ushort*)hs16, N);
  // final spmm L2 -> fp32 out
  k_spmm16<<<sb, 256, 0, stream>>>(hs16, csr, rofs, nd, CA + 2 * D, CB + 2 * D,
                                   (float*)d_out, N);
}